// Round 2
// baseline (1435.557 us; speedup 1.0000x reference)
//
#include <hip/hip_runtime.h>

#define HW 65536

// ---- ws layout (float offsets) ----
constexpr int OFF_X    = 0;          // 4*16*256*256
constexpr int OFF_CT   = 4194304;    // c transposed [b][g][w][h]
constexpr int OFF_MAX  = 8388608;
constexpr int OFF_SUM  = 12582912;
constexpr int OFF_MASK = 16777216;   // 262144
constexpr int P_K3  = 17039360;          // 256*8 softmax(scales2)
constexpr int P_K3S = P_K3  + 2048;      // shifted (j+4)%8
constexpr int P_K4  = P_K3S + 2048;      // 16*16 softmax(scales3)
constexpr int P_S1  = P_K4  + 256;       // softmax(scales1), 4
constexpr int P_BNS = P_S1  + 4;         // 16
constexpr int P_BNB = P_BNS + 16;        // 16
constexpr int P_WRI = P_BNB + 16;        // w_in  re-laid [ci][co] 1024
constexpr int P_WR0 = P_WRI + 1024;      // 256
constexpr int P_WR1 = P_WR0 + 256;       // 2304
constexpr int P_WR2 = P_WR1 + 2304;      // 6400
constexpr int P_WR3 = P_WR2 + 6400;      // 12544
constexpr int P_WRB = P_WR3 + 12544;     // 2304

__device__ __forceinline__ float sigmoid_fast(float x) {
  return __fdividef(1.0f, 1.0f + __expf(-x));
}

// ---------------- prep ----------------
__global__ void k_prep(const float* __restrict__ w_in, const float* __restrict__ w_c0,
                       const float* __restrict__ w_c1, const float* __restrict__ w_c2,
                       const float* __restrict__ w_c3, const float* __restrict__ w_base,
                       const float* __restrict__ scales1, const float* __restrict__ scales2,
                       const float* __restrict__ scales3, const float* __restrict__ bn_gamma,
                       const float* __restrict__ bn_beta, const float* __restrict__ bn_mean,
                       const float* __restrict__ bn_var, float* __restrict__ ws) {
  int tid = threadIdx.x;  // 256
  {
    const float* srow = scales2 + tid * 8;
    float v[8]; float mx = -1e30f;
    for (int j = 0; j < 8; j++) { v[j] = srow[j]; mx = fmaxf(mx, v[j]); }
    float s = 0.f;
    for (int j = 0; j < 8; j++) { v[j] = __expf(v[j] - mx); s += v[j]; }
    float inv = 1.0f / s;
    for (int j = 0; j < 8; j++) ws[P_K3 + tid * 8 + j] = v[j] * inv;
    for (int j = 0; j < 8; j++) ws[P_K3S + tid * 8 + j] = v[(j + 4) & 7] * inv;
  }
  if (tid < 16) {
    const float* srow = scales3 + tid * 16;
    float v[16]; float mx = -1e30f;
    for (int e = 0; e < 16; e++) { v[e] = srow[e]; mx = fmaxf(mx, v[e]); }
    float s = 0.f;
    for (int e = 0; e < 16; e++) { v[e] = __expf(v[e] - mx); s += v[e]; }
    float inv = 1.0f / s;
    for (int e = 0; e < 16; e++) ws[P_K4 + tid * 16 + e] = v[e] * inv;
  }
  if (tid == 0) {
    float v[4]; float mx = -1e30f;
    for (int i = 0; i < 4; i++) { v[i] = scales1[i]; mx = fmaxf(mx, v[i]); }
    float s = 0.f;
    for (int i = 0; i < 4; i++) { v[i] = __expf(v[i] - mx); s += v[i]; }
    for (int i = 0; i < 4; i++) ws[P_S1 + i] = v[i] / s;
  }
  if (tid < 16) {
    float rs = rsqrtf(bn_var[tid] + 1e-5f);
    float sc = bn_gamma[tid] * rs;
    ws[P_BNS + tid] = sc;
    ws[P_BNB + tid] = bn_beta[tid] - bn_mean[tid] * sc;
  }
  for (int i = tid; i < 1024; i += 256) { int ci = i >> 4, co = i & 15; ws[P_WRI + i] = w_in[co * 64 + ci]; }
  for (int i = tid; i < 256; i += 256)  { int ci = i >> 4, co = i & 15; ws[P_WR0 + i] = w_c0[co * 16 + ci]; }
  for (int i = tid; i < 2304; i += 256) {
    int co = i & 15; int r = i >> 4; int kw = r % 3; r /= 3; int kh = r % 3; int ci = r / 3;
    ws[P_WR1 + i] = w_c1[((co * 16 + ci) * 3 + kh) * 3 + kw];
  }
  for (int i = tid; i < 6400; i += 256) {
    int co = i & 15; int r = i >> 4; int kw = r % 5; r /= 5; int kh = r % 5; int ci = r / 5;
    ws[P_WR2 + i] = w_c2[((co * 16 + ci) * 5 + kh) * 5 + kw];
  }
  for (int i = tid; i < 12544; i += 256) {
    int co = i & 15; int r = i >> 4; int kw = r % 7; r /= 7; int kh = r % 7; int ci = r / 7;
    ws[P_WR3 + i] = w_c3[((co * 16 + ci) * 7 + kh) * 7 + kw];
  }
  // wbr[((g*3+kw)*3+kh)*16+co] = w_base[co][g][kh][kw]
  for (int i = tid; i < 2304; i += 256) {
    int co = i & 15; int r = i >> 4; int kh = r % 3; r /= 3; int kw = r % 3; int g = r / 3;
    ws[P_WRB + i] = w_base[((co * 16 + g) * 3 + kh) * 3 + kw];
  }
}

// ---------------- 1x1 conv 64->16 ----------------
__global__ __launch_bounds__(256) void k_in(const float* __restrict__ cen,
                                            const float* __restrict__ b_in,
                                            const float* __restrict__ ws,
                                            float* __restrict__ x) {
  int idx = blockIdx.x * 256 + threadIdx.x;  // pixel id
  int b = idx >> 16, p = idx & 65535;
  const float* wri = ws + P_WRI;
  float acc[16];
#pragma unroll
  for (int co = 0; co < 16; co++) acc[co] = b_in[co];
  const float* cp = cen + b * 64 * HW + p;
#pragma unroll 4
  for (int ci = 0; ci < 64; ci++) {
    float v = cp[ci * HW];
#pragma unroll
    for (int co = 0; co < 16; co++) acc[co] = fmaf(wri[ci * 16 + co], v, acc[co]);
  }
  float* xp = x + b * 16 * HW + p;
#pragma unroll
  for (int co = 0; co < 16; co++) xp[co * HW] = acc[co];
}

// ---------------- branch conv (k x k, 16->16), writes transposed c_T ----------------
template <int KS>
__global__ __launch_bounds__(256) void k_conv(const float* __restrict__ x,
                                              const float* __restrict__ bias,
                                              const float* __restrict__ wr,
                                              float* __restrict__ cT) {
  constexpr int P = KS / 2;
  constexpr int TS = 16 + KS - 1;
  __shared__ float lds[16 * TS * TS];
  __shared__ float ldso[16 * 16 * 16];
  int tid = threadIdx.x;
  int b = blockIdx.z;
  int hbase = blockIdx.y * 16, wbase = blockIdx.x * 16;
  const float* xb = x + b * 16 * HW;
  for (int i = tid; i < 16 * TS * TS; i += 256) {
    int ci = i / (TS * TS); int r = i % (TS * TS); int yy = r / TS, xx = r % TS;
    int h = hbase + yy - P, w = wbase + xx - P;
    float v = 0.0f;
    if (h >= 0 && h < 256 && w >= 0 && w < 256) v = xb[ci * HW + h * 256 + w];
    lds[i] = v;
  }
  __syncthreads();
  int y = tid >> 4, xcol = tid & 15;
  float acc[16];
#pragma unroll
  for (int co = 0; co < 16; co++) acc[co] = bias[co];
  for (int ci = 0; ci < 16; ci++) {
#pragma unroll
    for (int kh = 0; kh < KS; kh++) {
      const float* lrow = lds + ci * TS * TS + (y + kh) * TS + xcol;
#pragma unroll
      for (int kw = 0; kw < KS; kw++) {
        float v = lrow[kw];
        const float* wp = wr + ((ci * KS + kh) * KS + kw) * 16;
#pragma unroll
        for (int co = 0; co < 16; co++) acc[co] = fmaf(wp[co], v, acc[co]);
      }
    }
  }
#pragma unroll
  for (int co = 0; co < 16; co++) ldso[(co * 16 + xcol) * 16 + y] = acc[co];
  __syncthreads();
  for (int i = tid; i < 4096; i += 256) {
    int co = i >> 8, xw = (i >> 4) & 15, hh = i & 15;
    cT[((b * 16 + co) * 256 + (wbase + xw)) * 256 + hbase + hh] = ldso[(co * 16 + xw) * 16 + hh];
  }
}

// ---------------- bitonic sort of 256 values: 64 lanes x 4 regs, elem i = 4*lane + r ----------------
__device__ __forceinline__ void ce_pair(float& a, float& b, bool up) {
  float lo = fminf(a, b), hi = fmaxf(a, b);
  a = up ? lo : hi;
  b = up ? hi : lo;
}

template <int SIZE, int DIST>
__device__ __forceinline__ void stage_x(float v[4], int i0) {
  bool up = ((i0 & SIZE) == 0);
  bool keepmin = (((i0 & DIST) == 0) == up);
#pragma unroll
  for (int r = 0; r < 4; r++) {
    float pv = __shfl_xor(v[r], DIST >> 2, 64);
    float lo = fminf(v[r], pv), hi = fmaxf(v[r], pv);
    v[r] = keepmin ? lo : hi;
  }
}

template <int SIZE>
__device__ __forceinline__ void stage_d21(float v[4], int i0) {
  bool up = ((i0 & SIZE) == 0);
  ce_pair(v[0], v[2], up); ce_pair(v[1], v[3], up);
  ce_pair(v[0], v[1], up); ce_pair(v[2], v[3], up);
}

__device__ __forceinline__ void sort256(float v[4], int lane) {
  int i0 = lane << 2;
  ce_pair(v[0], v[1], true); ce_pair(v[2], v[3], false);   // size 2
  stage_d21<4>(v, i0);                                     // size 4
  stage_x<8, 4>(v, i0); stage_d21<8>(v, i0);
  stage_x<16, 8>(v, i0); stage_x<16, 4>(v, i0); stage_d21<16>(v, i0);
  stage_x<32, 16>(v, i0); stage_x<32, 8>(v, i0); stage_x<32, 4>(v, i0); stage_d21<32>(v, i0);
  stage_x<64, 32>(v, i0); stage_x<64, 16>(v, i0); stage_x<64, 8>(v, i0); stage_x<64, 4>(v, i0); stage_d21<64>(v, i0);
  stage_x<128, 64>(v, i0); stage_x<128, 32>(v, i0); stage_x<128, 16>(v, i0); stage_x<128, 8>(v, i0); stage_x<128, 4>(v, i0); stage_d21<128>(v, i0);
  stage_x<256, 128>(v, i0); stage_x<256, 64>(v, i0); stage_x<256, 32>(v, i0); stage_x<256, 16>(v, i0); stage_x<256, 8>(v, i0); stage_x<256, 4>(v, i0); stage_d21<256>(v, i0);
}

// ---------------- fused diff/k3/mul/sort/silu/k4 + branch max/sum accum ----------------
template <int DIL>
__global__ __launch_bounds__(256) void k_branch(const float* __restrict__ cT,
                                                const float* __restrict__ ws,
                                                float* __restrict__ maxb,
                                                float* __restrict__ sumb,
                                                int initFlag) {
  const int tid = threadIdx.x;
  const int lane = tid & 63;
  const int wv = (blockIdx.x << 2) + (tid >> 6);  // wave task id
  const int w = wv & 255;
  const int g = (wv >> 8) & 15;
  const int b = wv >> 12;
  const float* base = cT + ((b * 16 + g) << 16);

  float vals[3][3][4];
#pragma unroll
  for (int wi = 0; wi < 3; ++wi) {
    const int wc = w + (wi - 1) * DIL;
    const bool wok = ((unsigned)wc < 256u);
    const float* col = base + (wok ? wc : 0) * 256;
#pragma unroll
    for (int si = 0; si < 3; ++si) {
#pragma unroll
      for (int r = 0; r < 4; ++r) {
        const int h = lane + (r << 6) + (si - 1) * DIL;
        const bool ok = wok && ((unsigned)h < 256u);
        vals[wi][si][r] = ok ? col[h] : 0.0f;
      }
    }
  }
  float dd[8][4];
#pragma unroll
  for (int r = 0; r < 4; ++r) {
    const float c0 = vals[1][1][r];
    dd[0][r] = c0 - vals[0][0][r];  // (h-d, w-d)
    dd[1][r] = c0 - vals[1][0][r];  // (h-d, w)
    dd[2][r] = c0 - vals[2][0][r];  // (h-d, w+d)
    dd[3][r] = c0 - vals[0][1][r];  // (h,   w-d)
    dd[4][r] = c0 - vals[2][2][r];  // (h+d, w+d)
    dd[5][r] = c0 - vals[1][2][r];  // (h+d, w)
    dd[6][r] = c0 - vals[0][2][r];  // (h+d, w-d)
    dd[7][r] = c0 - vals[2][1][r];  // (h,   w+d)
  }
  float out[4] = {0.f, 0.f, 0.f, 0.f};
  const float* k3p  = ws + P_K3  + g * 128;
  const float* k3sp = ws + P_K3S + g * 128;
  const float* k4p  = ws + P_K4  + g * 16;
#pragma unroll 1
  for (int e = 0; e < 16; ++e) {
    float t[4];
#pragma unroll
    for (int r = 0; r < 4; ++r) {
      float o1 = k3p[e * 8] * dd[0][r];
      float o2 = k3sp[e * 8] * dd[0][r];
#pragma unroll
      for (int j = 1; j < 8; ++j) {
        o1 = fmaf(k3p[e * 8 + j], dd[j][r], o1);
        o2 = fmaf(k3sp[e * 8 + j], dd[j][r], o2);
      }
      t[r] = o1 * o2;
    }
    sort256(t, lane);
    const float k4v = k4p[e];
#pragma unroll
    for (int r = 0; r < 4; ++r) {
      const float v = t[r];
      out[r] = fmaf(k4v, v * sigmoid_fast(v), out[r]);
    }
  }
  const int obase = (((b * 16 + g) << 8) + w) * 256 + (lane << 2);
  float4 o4 = make_float4(out[0], out[1], out[2], out[3]);
  float4* mp = (float4*)(maxb + obase);
  float4* sp = (float4*)(sumb + obase);
  if (initFlag) {
    *mp = o4;
    *sp = o4;
  } else {
    float4 m = *mp;
    m.x = fmaxf(m.x, o4.x); m.y = fmaxf(m.y, o4.y);
    m.z = fmaxf(m.z, o4.z); m.w = fmaxf(m.w, o4.w);
    *mp = m;
    float4 s = *sp;
    s.x += o4.x; s.y += o4.y; s.z += o4.z; s.w += o4.w;
    *sp = s;
  }
}

// ---------------- combine + 3x3 conv + BN + SiLU + 1x1 + sigmoid -> mask ----------------
__global__ __launch_bounds__(256) void k_tail(const float* __restrict__ maxb,
                                              const float* __restrict__ sumb,
                                              const float* __restrict__ ws,
                                              float* __restrict__ mask,
                                              const float* __restrict__ w_out,
                                              const float* __restrict__ b_out) {
  __shared__ float lds[16 * 18 * 18];
  __shared__ float ldsm[256];
  int tid = threadIdx.x;
  int b = blockIdx.z;
  int wbase = blockIdx.x * 16, hbase = blockIdx.y * 16;
  const float* mb = maxb + (b * 16) * HW;  // [g][w][h]
  const float* sb = sumb + (b * 16) * HW;
  for (int i = tid; i < 16 * 18 * 18; i += 256) {
    int g = i / 324; int r = i % 324; int xx = r / 18, yy = r % 18;
    int wq = wbase + xx - 1, hq = hbase + yy - 1;
    float v = 0.0f;
    if (wq >= 0 && wq < 256 && hq >= 0 && hq < 256) {
      int idx = g * HW + wq * 256 + hq;
      v = mb[idx] + 0.25f * sb[idx];
    }
    lds[i] = v;
  }
  __syncthreads();
  int xw = tid >> 4, yh = tid & 15;  // pixel (w = wbase+xw, h = hbase+yh)
  float acc[16] = {0.f, 0.f, 0.f, 0.f, 0.f, 0.f, 0.f, 0.f,
                   0.f, 0.f, 0.f, 0.f, 0.f, 0.f, 0.f, 0.f};
  for (int g = 0; g < 16; g++) {
#pragma unroll
    for (int kw = 0; kw < 3; kw++) {
#pragma unroll
      for (int kh = 0; kh < 3; kh++) {
        float v = lds[g * 324 + (xw + kw) * 18 + (yh + kh)];
        const float* wp = ws + P_WRB + ((g * 3 + kw) * 3 + kh) * 16;
#pragma unroll
        for (int co = 0; co < 16; co++) acc[co] = fmaf(wp[co], v, acc[co]);
      }
    }
  }
  float mo = b_out[0];
#pragma unroll
  for (int co = 0; co < 16; co++) {
    float z = acc[co] * ws[P_BNS + co] + ws[P_BNB + co];
    float sl = z * sigmoid_fast(z);
    mo = fmaf(w_out[co], sl, mo);
  }
  float mk = sigmoid_fast(mo);
  ldsm[yh * 16 + xw] = mk;
  __syncthreads();
  int yy = tid >> 4, xx = tid & 15;
  mask[b * HW + (hbase + yy) * 256 + wbase + xx] = ldsm[yy * 16 + xx];
}

// ---------------- final elementwise gate ----------------
__global__ __launch_bounds__(256) void k_final(const float* __restrict__ cen,
                                               const float* __restrict__ mas,
                                               const float* __restrict__ mask,
                                               const float* __restrict__ ws,
                                               float* __restrict__ out) {
  int q = blockIdx.x * 256 + threadIdx.x;  // pixel-quad id
  int b = q >> 14;
  int off = (q & 16383) << 2;
  int cbase = blockIdx.y * 16;
  float s0 = ws[P_S1], s1 = ws[P_S1 + 1], s2 = ws[P_S1 + 2], s3 = ws[P_S1 + 3];
  const float4 mk4 = *(const float4*)(mask + b * HW + off);
  const float4 ms4 = *(const float4*)(mas + b * HW + off);
  float f[4];
  {
    float mks[4] = {mk4.x, mk4.y, mk4.z, mk4.w};
    float mss[4] = {ms4.x, ms4.y, ms4.z, ms4.w};
#pragma unroll
    for (int k = 0; k < 4; k++) {
      float m = sigmoid_fast(mss[k]);
      f[k] = mks[k] * m * s0 + m * s1 + s2 * mks[k] + s3;
    }
  }
#pragma unroll 4
  for (int ci = cbase; ci < cbase + 16; ci++) {
    const float4 c4 = *(const float4*)(cen + (b * 64 + ci) * HW + off);
    float4 o4;
    o4.x = c4.x * f[0]; o4.y = c4.y * f[1]; o4.z = c4.z * f[2]; o4.w = c4.w * f[3];
    *(float4*)(out + (b * 64 + ci) * HW + off) = o4;
  }
}

extern "C" void kernel_launch(void* const* d_in, const int* in_sizes, int n_in,
                              void* d_out, int out_size, void* d_ws, size_t ws_size,
                              hipStream_t stream) {
  (void)in_sizes; (void)n_in; (void)out_size; (void)ws_size;
  const float* cen = (const float*)d_in[0];
  const float* mas = (const float*)d_in[1];
  const float* w_in = (const float*)d_in[2];
  const float* b_in = (const float*)d_in[3];
  const float* w_c0 = (const float*)d_in[4];
  const float* b_c0 = (const float*)d_in[5];
  const float* w_c1 = (const float*)d_in[6];
  const float* b_c1 = (const float*)d_in[7];
  const float* w_c2 = (const float*)d_in[8];
  const float* b_c2 = (const float*)d_in[9];
  const float* w_c3 = (const float*)d_in[10];
  const float* b_c3 = (const float*)d_in[11];
  const float* scales1 = (const float*)d_in[12];
  const float* scales2 = (const float*)d_in[13];
  const float* scales3 = (const float*)d_in[14];
  const float* w_base = (const float*)d_in[15];
  const float* bn_gamma = (const float*)d_in[16];
  const float* bn_beta = (const float*)d_in[17];
  const float* bn_mean = (const float*)d_in[18];
  const float* bn_var = (const float*)d_in[19];
  const float* w_out = (const float*)d_in[20];
  const float* b_out = (const float*)d_in[21];
  float* ws = (float*)d_ws;
  float* out = (float*)d_out;

  float* x = ws + OFF_X;
  float* cT = ws + OFF_CT;
  float* maxb = ws + OFF_MAX;
  float* sumb = ws + OFF_SUM;
  float* mask = ws + OFF_MASK;

  k_prep<<<1, 256, 0, stream>>>(w_in, w_c0, w_c1, w_c2, w_c3, w_base, scales1, scales2,
                                scales3, bn_gamma, bn_beta, bn_mean, bn_var, ws);
  k_in<<<1024, 256, 0, stream>>>(cen, b_in, ws, x);

  dim3 cg(16, 16, 4);
  k_conv<1><<<cg, 256, 0, stream>>>(x, b_c0, ws + P_WR0, cT);
  k_branch<1><<<4096, 256, 0, stream>>>(cT, ws, maxb, sumb, 1);
  k_conv<3><<<cg, 256, 0, stream>>>(x, b_c1, ws + P_WR1, cT);
  k_branch<3><<<4096, 256, 0, stream>>>(cT, ws, maxb, sumb, 0);
  k_conv<5><<<cg, 256, 0, stream>>>(x, b_c2, ws + P_WR2, cT);
  k_branch<5><<<4096, 256, 0, stream>>>(cT, ws, maxb, sumb, 0);
  k_conv<7><<<cg, 256, 0, stream>>>(x, b_c3, ws + P_WR3, cT);
  k_branch<7><<<4096, 256, 0, stream>>>(cT, ws, maxb, sumb, 0);

  k_tail<<<cg, 256, 0, stream>>>(maxb, sumb, ws, mask, w_out, b_out);
  k_final<<<dim3(256, 4), 256, 0, stream>>>(cen, mas, mask, ws, out);
}

// Round 5
// 1092.323 us; speedup vs baseline: 1.3142x; 1.3142x over previous
//
#include <hip/hip_runtime.h>

#define HW 65536

// ---- ws layout (float offsets) ----
constexpr int OFF_X    = 0;          // 4*16*256*256
constexpr int OFF_CT   = 4194304;    // c transposed [b][g][w][h]
constexpr int OFF_MAX  = 8388608;
constexpr int OFF_SUM  = 12582912;
constexpr int OFF_MASK = 16777216;   // 262144
constexpr int P_K3  = 17039360;          // 256*8 softmax(scales2)
constexpr int P_K3S = P_K3  + 2048;      // shifted (j+4)%8
constexpr int P_K4  = P_K3S + 2048;      // 16*16 softmax(scales3)
constexpr int P_S1  = P_K4  + 256;       // softmax(scales1), 4
constexpr int P_BNS = P_S1  + 4;         // 16
constexpr int P_BNB = P_BNS + 16;        // 16
constexpr int P_WRI = P_BNB + 16;        // w_in  re-laid [ci][co] 1024
constexpr int P_WR0 = P_WRI + 1024;      // 256
constexpr int P_WR1 = P_WR0 + 256;       // 2304
constexpr int P_WR2 = P_WR1 + 2304;      // 6400
constexpr int P_WR3 = P_WR2 + 6400;      // 12544
constexpr int P_WRB = P_WR3 + 12544;     // 2304
constexpr int P_K3H  = P_WRB + 2304;     // packed fp16 pairs: 16g*8p*8j = 1024 (uint32)
constexpr int P_K3SH = P_K3H + 1024;     // 1024

// clang-native packed fp16 (avoids broken __hmin2/__hmax2 overloads in ROCm header)
typedef _Float16 hv2 __attribute__((ext_vector_type(2)));

__device__ __forceinline__ int h2i(hv2 v) { return __builtin_bit_cast(int, v); }
__device__ __forceinline__ hv2 i2h(int v) { return __builtin_bit_cast(hv2, v); }

// __builtin_amdgcn_cvt_pkrtz returns __fp16 ext_vector(2); bit-cast to hv2
__device__ __forceinline__ hv2 pkrtz(float a, float b) {
  return __builtin_bit_cast(hv2, __builtin_amdgcn_cvt_pkrtz(a, b));
}

__device__ __forceinline__ hv2 pk_fma(hv2 a, hv2 b, hv2 c) {
#if __has_builtin(__builtin_elementwise_fma)
  return __builtin_elementwise_fma(a, b, c);
#else
  return a * b + c;  // fp-contract fuses to v_pk_fma_f16
#endif
}

__device__ __forceinline__ float sigmoid_fast(float x) {
  return __fdividef(1.0f, 1.0f + __expf(-x));
}

// ---------------- prep ----------------
__global__ void k_prep(const float* __restrict__ w_in, const float* __restrict__ w_c0,
                       const float* __restrict__ w_c1, const float* __restrict__ w_c2,
                       const float* __restrict__ w_c3, const float* __restrict__ w_base,
                       const float* __restrict__ scales1, const float* __restrict__ scales2,
                       const float* __restrict__ scales3, const float* __restrict__ bn_gamma,
                       const float* __restrict__ bn_beta, const float* __restrict__ bn_mean,
                       const float* __restrict__ bn_var, float* __restrict__ ws) {
  int tid = threadIdx.x;  // 256
  {
    const float* srow = scales2 + tid * 8;
    float v[8]; float mx = -1e30f;
    for (int j = 0; j < 8; j++) { v[j] = srow[j]; mx = fmaxf(mx, v[j]); }
    float s = 0.f;
    for (int j = 0; j < 8; j++) { v[j] = __expf(v[j] - mx); s += v[j]; }
    float inv = 1.0f / s;
    for (int j = 0; j < 8; j++) ws[P_K3 + tid * 8 + j] = v[j] * inv;
    for (int j = 0; j < 8; j++) ws[P_K3S + tid * 8 + j] = v[(j + 4) & 7] * inv;
  }
  if (tid < 16) {
    const float* srow = scales3 + tid * 16;
    float v[16]; float mx = -1e30f;
    for (int e = 0; e < 16; e++) { v[e] = srow[e]; mx = fmaxf(mx, v[e]); }
    float s = 0.f;
    for (int e = 0; e < 16; e++) { v[e] = __expf(v[e] - mx); s += v[e]; }
    float inv = 1.0f / s;
    for (int e = 0; e < 16; e++) ws[P_K4 + tid * 16 + e] = v[e] * inv;
  }
  if (tid == 0) {
    float v[4]; float mx = -1e30f;
    for (int i = 0; i < 4; i++) { v[i] = scales1[i]; mx = fmaxf(mx, v[i]); }
    float s = 0.f;
    for (int i = 0; i < 4; i++) { v[i] = __expf(v[i] - mx); s += v[i]; }
    for (int i = 0; i < 4; i++) ws[P_S1 + i] = v[i] / s;
  }
  if (tid < 16) {
    float rs = rsqrtf(bn_var[tid] + 1e-5f);
    float sc = bn_gamma[tid] * rs;
    ws[P_BNS + tid] = sc;
    ws[P_BNB + tid] = bn_beta[tid] - bn_mean[tid] * sc;
  }
  for (int i = tid; i < 1024; i += 256) { int ci = i >> 4, co = i & 15; ws[P_WRI + i] = w_in[co * 64 + ci]; }
  for (int i = tid; i < 256; i += 256)  { int ci = i >> 4, co = i & 15; ws[P_WR0 + i] = w_c0[co * 16 + ci]; }
  for (int i = tid; i < 2304; i += 256) {
    int co = i & 15; int r = i >> 4; int kw = r % 3; r /= 3; int kh = r % 3; int ci = r / 3;
    ws[P_WR1 + i] = w_c1[((co * 16 + ci) * 3 + kh) * 3 + kw];
  }
  for (int i = tid; i < 6400; i += 256) {
    int co = i & 15; int r = i >> 4; int kw = r % 5; r /= 5; int kh = r % 5; int ci = r / 5;
    ws[P_WR2 + i] = w_c2[((co * 16 + ci) * 5 + kh) * 5 + kw];
  }
  for (int i = tid; i < 12544; i += 256) {
    int co = i & 15; int r = i >> 4; int kw = r % 7; r /= 7; int kh = r % 7; int ci = r / 7;
    ws[P_WR3 + i] = w_c3[((co * 16 + ci) * 7 + kh) * 7 + kw];
  }
  // wbr[((g*3+kw)*3+kh)*16+co] = w_base[co][g][kh][kw]
  for (int i = tid; i < 2304; i += 256) {
    int co = i & 15; int r = i >> 4; int kh = r % 3; r /= 3; int kw = r % 3; int g = r / 3;
    ws[P_WRB + i] = w_base[((co * 16 + g) * 3 + kh) * 3 + kw];
  }
  __syncthreads();
  // packed fp16 k3 weights: idx -> g (idx>>6), p ((idx>>3)&7), j (idx&7)
  // low half = e=2p, high half = e=2p+1  (RN via _Float16 casts)
  uint32_t* k3h  = (uint32_t*)(ws + P_K3H);
  uint32_t* k3sh = (uint32_t*)(ws + P_K3SH);
  for (int i = tid; i < 1024; i += 256) {
    int g = i >> 6, p = (i >> 3) & 7, j = i & 7;
    hv2 wv, wvs;
    wv.x  = (_Float16)ws[P_K3 + g * 128 + (2 * p) * 8 + j];
    wv.y  = (_Float16)ws[P_K3 + g * 128 + (2 * p + 1) * 8 + j];
    wvs.x = (_Float16)ws[P_K3S + g * 128 + (2 * p) * 8 + j];
    wvs.y = (_Float16)ws[P_K3S + g * 128 + (2 * p + 1) * 8 + j];
    k3h[i]  = __builtin_bit_cast(uint32_t, wv);
    k3sh[i] = __builtin_bit_cast(uint32_t, wvs);
  }
}

// ---------------- 1x1 conv 64->16 ----------------
__global__ __launch_bounds__(256) void k_in(const float* __restrict__ cen,
                                            const float* __restrict__ b_in,
                                            const float* __restrict__ ws,
                                            float* __restrict__ x) {
  int idx = blockIdx.x * 256 + threadIdx.x;  // pixel id
  int b = idx >> 16, p = idx & 65535;
  const float* wri = ws + P_WRI;
  float acc[16];
#pragma unroll
  for (int co = 0; co < 16; co++) acc[co] = b_in[co];
  const float* cp = cen + b * 64 * HW + p;
#pragma unroll 4
  for (int ci = 0; ci < 64; ci++) {
    float v = cp[ci * HW];
#pragma unroll
    for (int co = 0; co < 16; co++) acc[co] = fmaf(wri[ci * 16 + co], v, acc[co]);
  }
  float* xp = x + b * 16 * HW + p;
#pragma unroll
  for (int co = 0; co < 16; co++) xp[co * HW] = acc[co];
}

// ---------------- branch conv (k x k, 16->16), writes transposed c_T ----------------
template <int KS>
__global__ __launch_bounds__(256) void k_conv(const float* __restrict__ x,
                                              const float* __restrict__ bias,
                                              const float* __restrict__ wr,
                                              float* __restrict__ cT) {
  constexpr int P = KS / 2;
  constexpr int TS = 16 + KS - 1;
  __shared__ float lds[16 * TS * TS];
  __shared__ float ldso[16 * 16 * 16];
  int tid = threadIdx.x;
  int b = blockIdx.z;
  int hbase = blockIdx.y * 16, wbase = blockIdx.x * 16;
  const float* xb = x + b * 16 * HW;
  for (int i = tid; i < 16 * TS * TS; i += 256) {
    int ci = i / (TS * TS); int r = i % (TS * TS); int yy = r / TS, xx = r % TS;
    int h = hbase + yy - P, w = wbase + xx - P;
    float v = 0.0f;
    if (h >= 0 && h < 256 && w >= 0 && w < 256) v = xb[ci * HW + h * 256 + w];
    lds[i] = v;
  }
  __syncthreads();
  int y = tid >> 4, xcol = tid & 15;
  float acc[16];
#pragma unroll
  for (int co = 0; co < 16; co++) acc[co] = bias[co];
  for (int ci = 0; ci < 16; ci++) {
#pragma unroll
    for (int kh = 0; kh < KS; kh++) {
      const float* lrow = lds + ci * TS * TS + (y + kh) * TS + xcol;
#pragma unroll
      for (int kw = 0; kw < KS; kw++) {
        float v = lrow[kw];
        const float* wp = wr + ((ci * KS + kh) * KS + kw) * 16;
#pragma unroll
        for (int co = 0; co < 16; co++) acc[co] = fmaf(wp[co], v, acc[co]);
      }
    }
  }
#pragma unroll
  for (int co = 0; co < 16; co++) ldso[(co * 16 + xcol) * 16 + y] = acc[co];
  __syncthreads();
  for (int i = tid; i < 4096; i += 256) {
    int co = i >> 8, xw = (i >> 4) & 15, hh = i & 15;
    cT[((b * 16 + co) * 256 + (wbase + xw)) * 256 + hbase + hh] = ldso[(co * 16 + xw) * 16 + hh];
  }
}

// ---------------- packed-fp16 bitonic sort of 256 values: 64 lanes x 4 regs ----------------
// element i = 4*lane + r; each hv2 register sorts TWO independent channels in lockstep
__device__ __forceinline__ void ce_pair_h(hv2& a, hv2& b, bool up) {
  hv2 lo = __builtin_elementwise_min(a, b);
  hv2 hi = __builtin_elementwise_max(a, b);
  a = up ? lo : hi;
  b = up ? hi : lo;
}

template <int SIZE, int DIST>
__device__ __forceinline__ void stage_x_h(hv2 v[4], int i0) {
  const bool keepmin = (((i0 & DIST) == 0) == ((i0 & SIZE) == 0));
#pragma unroll
  for (int r = 0; r < 4; r++) {
    hv2 pv = i2h(__shfl_xor(h2i(v[r]), DIST >> 2, 64));
    hv2 lo = __builtin_elementwise_min(v[r], pv);
    hv2 hi = __builtin_elementwise_max(v[r], pv);
    v[r] = keepmin ? lo : hi;
  }
}

template <int SIZE>
__device__ __forceinline__ void stage_d21_h(hv2 v[4], int i0) {
  bool up = ((i0 & SIZE) == 0);
  ce_pair_h(v[0], v[2], up); ce_pair_h(v[1], v[3], up);
  ce_pair_h(v[0], v[1], up); ce_pair_h(v[2], v[3], up);
}

__device__ __forceinline__ void sort256h(hv2 v[4], int lane) {
  int i0 = lane << 2;
  ce_pair_h(v[0], v[1], true); ce_pair_h(v[2], v[3], false);   // size 2
  stage_d21_h<4>(v, i0);                                       // size 4
  stage_x_h<8, 4>(v, i0); stage_d21_h<8>(v, i0);
  stage_x_h<16, 8>(v, i0); stage_x_h<16, 4>(v, i0); stage_d21_h<16>(v, i0);
  stage_x_h<32, 16>(v, i0); stage_x_h<32, 8>(v, i0); stage_x_h<32, 4>(v, i0); stage_d21_h<32>(v, i0);
  stage_x_h<64, 32>(v, i0); stage_x_h<64, 16>(v, i0); stage_x_h<64, 8>(v, i0); stage_x_h<64, 4>(v, i0); stage_d21_h<64>(v, i0);
  stage_x_h<128, 64>(v, i0); stage_x_h<128, 32>(v, i0); stage_x_h<128, 16>(v, i0); stage_x_h<128, 8>(v, i0); stage_x_h<128, 4>(v, i0); stage_d21_h<128>(v, i0);
  stage_x_h<256, 128>(v, i0); stage_x_h<256, 64>(v, i0); stage_x_h<256, 32>(v, i0); stage_x_h<256, 16>(v, i0); stage_x_h<256, 8>(v, i0); stage_x_h<256, 4>(v, i0); stage_d21_h<256>(v, i0);
}

// ---------------- fused diff/k3/mul/sort/silu/k4 + branch max/sum accum ----------------
template <int DIL>
__global__ __launch_bounds__(256) void k_branch(const float* __restrict__ cT,
                                                const float* __restrict__ ws,
                                                float* __restrict__ maxb,
                                                float* __restrict__ sumb,
                                                int initFlag) {
  const int tid = threadIdx.x;
  const int lane = tid & 63;
  const int wv = (blockIdx.x << 2) + (tid >> 6);  // wave task id
  const int w = wv & 255;
  const int g = (wv >> 8) & 15;
  const int b = wv >> 12;
  const float* base = cT + ((b * 16 + g) << 16);

  float vals[3][3][4];
#pragma unroll
  for (int wi = 0; wi < 3; ++wi) {
    const int wc = w + (wi - 1) * DIL;
    const bool wok = ((unsigned)wc < 256u);
    const float* col = base + (wok ? wc : 0) * 256;
#pragma unroll
    for (int si = 0; si < 3; ++si) {
#pragma unroll
      for (int r = 0; r < 4; ++r) {
        const int h = lane + (r << 6) + (si - 1) * DIL;
        const bool ok = wok && ((unsigned)h < 256u);
        vals[wi][si][r] = ok ? col[h] : 0.0f;
      }
    }
  }
  // directional differences (fp32), then broadcast-pack to fp16x2 (one v_cvt_pkrtz each)
  hv2 ddh[8][4];
#pragma unroll
  for (int r = 0; r < 4; ++r) {
    const float c0 = vals[1][1][r];
    float d0 = c0 - vals[0][0][r];  // (h-d, w-d)
    float d1 = c0 - vals[1][0][r];  // (h-d, w)
    float d2 = c0 - vals[2][0][r];  // (h-d, w+d)
    float d3 = c0 - vals[0][1][r];  // (h,   w-d)
    float d4 = c0 - vals[2][2][r];  // (h+d, w+d)
    float d5 = c0 - vals[1][2][r];  // (h+d, w)
    float d6 = c0 - vals[0][2][r];  // (h+d, w-d)
    float d7 = c0 - vals[2][1][r];  // (h,   w+d)
    ddh[0][r] = pkrtz(d0, d0);
    ddh[1][r] = pkrtz(d1, d1);
    ddh[2][r] = pkrtz(d2, d2);
    ddh[3][r] = pkrtz(d3, d3);
    ddh[4][r] = pkrtz(d4, d4);
    ddh[5][r] = pkrtz(d5, d5);
    ddh[6][r] = pkrtz(d6, d6);
    ddh[7][r] = pkrtz(d7, d7);
  }
  float out[4] = {0.f, 0.f, 0.f, 0.f};
  const uint32_t* k3h  = (const uint32_t*)(ws + P_K3H)  + g * 64;
  const uint32_t* k3sh = (const uint32_t*)(ws + P_K3SH) + g * 64;
  const float* k4p = ws + P_K4 + g * 16;
#pragma unroll 1
  for (int p = 0; p < 8; ++p) {
    hv2 t[4];
#pragma unroll
    for (int r = 0; r < 4; ++r) {
      hv2 o1 = __builtin_bit_cast(hv2, k3h[p * 8]) * ddh[0][r];
      hv2 o2 = __builtin_bit_cast(hv2, k3sh[p * 8]) * ddh[0][r];
#pragma unroll
      for (int j = 1; j < 8; ++j) {
        o1 = pk_fma(__builtin_bit_cast(hv2, k3h[p * 8 + j]), ddh[j][r], o1);
        o2 = pk_fma(__builtin_bit_cast(hv2, k3sh[p * 8 + j]), ddh[j][r], o2);
      }
      t[r] = o1 * o2;
    }
    sort256h(t, lane);
    const float k4a = k4p[2 * p], k4b = k4p[2 * p + 1];
#pragma unroll
    for (int r = 0; r < 4; ++r) {
      const float va = (float)t[r].x;
      const float vb = (float)t[r].y;
      out[r] = fmaf(k4a, va * sigmoid_fast(va), out[r]);
      out[r] = fmaf(k4b, vb * sigmoid_fast(vb), out[r]);
    }
  }
  const int obase = (((b * 16 + g) << 8) + w) * 256 + (lane << 2);
  float4 o4 = make_float4(out[0], out[1], out[2], out[3]);
  float4* mp = (float4*)(maxb + obase);
  float4* sp = (float4*)(sumb + obase);
  if (initFlag) {
    *mp = o4;
    *sp = o4;
  } else {
    float4 m = *mp;
    m.x = fmaxf(m.x, o4.x); m.y = fmaxf(m.y, o4.y);
    m.z = fmaxf(m.z, o4.z); m.w = fmaxf(m.w, o4.w);
    *mp = m;
    float4 s = *sp;
    s.x += o4.x; s.y += o4.y; s.z += o4.z; s.w += o4.w;
    *sp = s;
  }
}

// ---------------- combine + 3x3 conv + BN + SiLU + 1x1 + sigmoid -> mask ----------------
__global__ __launch_bounds__(256) void k_tail(const float* __restrict__ maxb,
                                              const float* __restrict__ sumb,
                                              const float* __restrict__ ws,
                                              float* __restrict__ mask,
                                              const float* __restrict__ w_out,
                                              const float* __restrict__ b_out) {
  __shared__ float lds[16 * 18 * 18];
  __shared__ float ldsm[256];
  int tid = threadIdx.x;
  int b = blockIdx.z;
  int wbase = blockIdx.x * 16, hbase = blockIdx.y * 16;
  const float* mb = maxb + (b * 16) * HW;  // [g][w][h]
  const float* sb = sumb + (b * 16) * HW;
  for (int i = tid; i < 16 * 18 * 18; i += 256) {
    int g = i / 324; int r = i % 324; int xx = r / 18, yy = r % 18;
    int wq = wbase + xx - 1, hq = hbase + yy - 1;
    float v = 0.0f;
    if (wq >= 0 && wq < 256 && hq >= 0 && hq < 256) {
      int idx = g * HW + wq * 256 + hq;
      v = mb[idx] + 0.25f * sb[idx];
    }
    lds[i] = v;
  }
  __syncthreads();
  int xw = tid >> 4, yh = tid & 15;  // pixel (w = wbase+xw, h = hbase+yh)
  float acc[16] = {0.f, 0.f, 0.f, 0.f, 0.f, 0.f, 0.f, 0.f,
                   0.f, 0.f, 0.f, 0.f, 0.f, 0.f, 0.f, 0.f};
  for (int g = 0; g < 16; g++) {
#pragma unroll
    for (int kw = 0; kw < 3; kw++) {
#pragma unroll
      for (int kh = 0; kh < 3; kh++) {
        float v = lds[g * 324 + (xw + kw) * 18 + (yh + kh)];
        const float* wp = ws + P_WRB + ((g * 3 + kw) * 3 + kh) * 16;
#pragma unroll
        for (int co = 0; co < 16; co++) acc[co] = fmaf(wp[co], v, acc[co]);
      }
    }
  }
  float mo = b_out[0];
#pragma unroll
  for (int co = 0; co < 16; co++) {
    float z = acc[co] * ws[P_BNS + co] + ws[P_BNB + co];
    float sl = z * sigmoid_fast(z);
    mo = fmaf(w_out[co], sl, mo);
  }
  float mk = sigmoid_fast(mo);
  ldsm[yh * 16 + xw] = mk;
  __syncthreads();
  int yy = tid >> 4, xx = tid & 15;
  mask[b * HW + (hbase + yy) * 256 + wbase + xx] = ldsm[yy * 16 + xx];
}

// ---------------- final elementwise gate ----------------
__global__ __launch_bounds__(256) void k_final(const float* __restrict__ cen,
                                               const float* __restrict__ mas,
                                               const float* __restrict__ mask,
                                               const float* __restrict__ ws,
                                               float* __restrict__ out) {
  int q = blockIdx.x * 256 + threadIdx.x;  // pixel-quad id
  int b = q >> 14;
  int off = (q & 16383) << 2;
  int cbase = blockIdx.y * 16;
  float s0 = ws[P_S1], s1 = ws[P_S1 + 1], s2 = ws[P_S1 + 2], s3 = ws[P_S1 + 3];
  const float4 mk4 = *(const float4*)(mask + b * HW + off);
  const float4 ms4 = *(const float4*)(mas + b * HW + off);
  float f[4];
  {
    float mks[4] = {mk4.x, mk4.y, mk4.z, mk4.w};
    float mss[4] = {ms4.x, ms4.y, ms4.z, ms4.w};
#pragma unroll
    for (int k = 0; k < 4; k++) {
      float m = sigmoid_fast(mss[k]);
      f[k] = mks[k] * m * s0 + m * s1 + s2 * mks[k] + s3;
    }
  }
#pragma unroll 4
  for (int ci = cbase; ci < cbase + 16; ci++) {
    const float4 c4 = *(const float4*)(cen + (b * 64 + ci) * HW + off);
    float4 o4;
    o4.x = c4.x * f[0]; o4.y = c4.y * f[1]; o4.z = c4.z * f[2]; o4.w = c4.w * f[3];
    *(float4*)(out + (b * 64 + ci) * HW + off) = o4;
  }
}

extern "C" void kernel_launch(void* const* d_in, const int* in_sizes, int n_in,
                              void* d_out, int out_size, void* d_ws, size_t ws_size,
                              hipStream_t stream) {
  (void)in_sizes; (void)n_in; (void)out_size; (void)ws_size;
  const float* cen = (const float*)d_in[0];
  const float* mas = (const float*)d_in[1];
  const float* w_in = (const float*)d_in[2];
  const float* b_in = (const float*)d_in[3];
  const float* w_c0 = (const float*)d_in[4];
  const float* b_c0 = (const float*)d_in[5];
  const float* w_c1 = (const float*)d_in[6];
  const float* b_c1 = (const float*)d_in[7];
  const float* w_c2 = (const float*)d_in[8];
  const float* b_c2 = (const float*)d_in[9];
  const float* w_c3 = (const float*)d_in[10];
  const float* b_c3 = (const float*)d_in[11];
  const float* scales1 = (const float*)d_in[12];
  const float* scales2 = (const float*)d_in[13];
  const float* scales3 = (const float*)d_in[14];
  const float* w_base = (const float*)d_in[15];
  const float* bn_gamma = (const float*)d_in[16];
  const float* bn_beta = (const float*)d_in[17];
  const float* bn_mean = (const float*)d_in[18];
  const float* bn_var = (const float*)d_in[19];
  const float* w_out = (const float*)d_in[20];
  const float* b_out = (const float*)d_in[21];
  float* ws = (float*)d_ws;
  float* out = (float*)d_out;

  float* x = ws + OFF_X;
  float* cT = ws + OFF_CT;
  float* maxb = ws + OFF_MAX;
  float* sumb = ws + OFF_SUM;
  float* mask = ws + OFF_MASK;

  k_prep<<<1, 256, 0, stream>>>(w_in, w_c0, w_c1, w_c2, w_c3, w_base, scales1, scales2,
                                scales3, bn_gamma, bn_beta, bn_mean, bn_var, ws);
  k_in<<<1024, 256, 0, stream>>>(cen, b_in, ws, x);

  dim3 cg(16, 16, 4);
  k_conv<1><<<cg, 256, 0, stream>>>(x, b_c0, ws + P_WR0, cT);
  k_branch<1><<<4096, 256, 0, stream>>>(cT, ws, maxb, sumb, 1);
  k_conv<3><<<cg, 256, 0, stream>>>(x, b_c1, ws + P_WR1, cT);
  k_branch<3><<<4096, 256, 0, stream>>>(cT, ws, maxb, sumb, 0);
  k_conv<5><<<cg, 256, 0, stream>>>(x, b_c2, ws + P_WR2, cT);
  k_branch<5><<<4096, 256, 0, stream>>>(cT, ws, maxb, sumb, 0);
  k_conv<7><<<cg, 256, 0, stream>>>(x, b_c3, ws + P_WR3, cT);
  k_branch<7><<<4096, 256, 0, stream>>>(cT, ws, maxb, sumb, 0);

  k_tail<<<cg, 256, 0, stream>>>(maxb, sumb, ws, mask, w_out, b_out);
  k_final<<<dim3(256, 4), 256, 0, stream>>>(cen, mas, mask, ws, out);
}

// Round 6
// 974.991 us; speedup vs baseline: 1.4724x; 1.1203x over previous
//
#include <hip/hip_runtime.h>

#define HW 65536

// ---- ws layout (float offsets) ----
constexpr int OFF_X    = 0;          // xT: 4b*16ci*256w*256h (transposed)
constexpr int OFF_CT   = 4194304;    // c transposed [b][g][w][h]
constexpr int OFF_MAX  = 8388608;
constexpr int OFF_SUM  = 12582912;
constexpr int OFF_MASK = 16777216;   // 262144
constexpr int P_K3  = 17039360;          // 256*8 softmax(scales2)
constexpr int P_K3S = P_K3  + 2048;      // shifted (j+4)%8
constexpr int P_K4  = P_K3S + 2048;      // 16*16 softmax(scales3)
constexpr int P_S1  = P_K4  + 256;       // softmax(scales1), 4
constexpr int P_BNS = P_S1  + 4;         // 16
constexpr int P_BNB = P_BNS + 16;        // 16
constexpr int P_WRI = P_BNB + 16;        // w_in  re-laid [ci][co] 1024
constexpr int P_WR0 = P_WRI + 1024;      // 256
constexpr int P_WR1 = P_WR0 + 256;       // 2304
constexpr int P_WR2 = P_WR1 + 2304;      // 6400
constexpr int P_WR3 = P_WR2 + 6400;      // 12544
constexpr int P_WRB = P_WR3 + 12544;     // 2304
constexpr int P_K3H  = P_WRB + 2304;     // packed fp16 pairs: 16g*8p*8j = 1024 (uint32)
constexpr int P_K3SH = P_K3H + 1024;     // 1024

// clang-native packed fp16 (avoids broken __hmin2/__hmax2 overloads in ROCm header)
typedef _Float16 hv2 __attribute__((ext_vector_type(2)));

__device__ __forceinline__ int h2i(hv2 v) { return __builtin_bit_cast(int, v); }
__device__ __forceinline__ hv2 i2h(int v) { return __builtin_bit_cast(hv2, v); }

// __builtin_amdgcn_cvt_pkrtz returns __fp16 ext_vector(2); bit-cast to hv2
__device__ __forceinline__ hv2 pkrtz(float a, float b) {
  return __builtin_bit_cast(hv2, __builtin_amdgcn_cvt_pkrtz(a, b));
}

__device__ __forceinline__ hv2 pk_fma(hv2 a, hv2 b, hv2 c) {
#if __has_builtin(__builtin_elementwise_fma)
  return __builtin_elementwise_fma(a, b, c);
#else
  return a * b + c;  // fp-contract fuses to v_pk_fma_f16
#endif
}

__device__ __forceinline__ float sigmoid_fast(float x) {
  return __fdividef(1.0f, 1.0f + __expf(-x));
}

// ---------------- prep ----------------
__global__ void k_prep(const float* __restrict__ w_in, const float* __restrict__ w_c0,
                       const float* __restrict__ w_c1, const float* __restrict__ w_c2,
                       const float* __restrict__ w_c3, const float* __restrict__ w_base,
                       const float* __restrict__ scales1, const float* __restrict__ scales2,
                       const float* __restrict__ scales3, const float* __restrict__ bn_gamma,
                       const float* __restrict__ bn_beta, const float* __restrict__ bn_mean,
                       const float* __restrict__ bn_var, float* __restrict__ ws) {
  int tid = threadIdx.x;  // 256
  {
    const float* srow = scales2 + tid * 8;
    float v[8]; float mx = -1e30f;
    for (int j = 0; j < 8; j++) { v[j] = srow[j]; mx = fmaxf(mx, v[j]); }
    float s = 0.f;
    for (int j = 0; j < 8; j++) { v[j] = __expf(v[j] - mx); s += v[j]; }
    float inv = 1.0f / s;
    for (int j = 0; j < 8; j++) ws[P_K3 + tid * 8 + j] = v[j] * inv;
    for (int j = 0; j < 8; j++) ws[P_K3S + tid * 8 + j] = v[(j + 4) & 7] * inv;
  }
  if (tid < 16) {
    const float* srow = scales3 + tid * 16;
    float v[16]; float mx = -1e30f;
    for (int e = 0; e < 16; e++) { v[e] = srow[e]; mx = fmaxf(mx, v[e]); }
    float s = 0.f;
    for (int e = 0; e < 16; e++) { v[e] = __expf(v[e] - mx); s += v[e]; }
    float inv = 1.0f / s;
    for (int e = 0; e < 16; e++) ws[P_K4 + tid * 16 + e] = v[e] * inv;
  }
  if (tid == 0) {
    float v[4]; float mx = -1e30f;
    for (int i = 0; i < 4; i++) { v[i] = scales1[i]; mx = fmaxf(mx, v[i]); }
    float s = 0.f;
    for (int i = 0; i < 4; i++) { v[i] = __expf(v[i] - mx); s += v[i]; }
    for (int i = 0; i < 4; i++) ws[P_S1 + i] = v[i] / s;
  }
  if (tid < 16) {
    float rs = rsqrtf(bn_var[tid] + 1e-5f);
    float sc = bn_gamma[tid] * rs;
    ws[P_BNS + tid] = sc;
    ws[P_BNB + tid] = bn_beta[tid] - bn_mean[tid] * sc;
  }
  for (int i = tid; i < 1024; i += 256) { int ci = i >> 4, co = i & 15; ws[P_WRI + i] = w_in[co * 64 + ci]; }
  for (int i = tid; i < 256; i += 256)  { int ci = i >> 4, co = i & 15; ws[P_WR0 + i] = w_c0[co * 16 + ci]; }
  for (int i = tid; i < 2304; i += 256) {
    int co = i & 15; int r = i >> 4; int kw = r % 3; r /= 3; int kh = r % 3; int ci = r / 3;
    ws[P_WR1 + i] = w_c1[((co * 16 + ci) * 3 + kh) * 3 + kw];
  }
  for (int i = tid; i < 6400; i += 256) {
    int co = i & 15; int r = i >> 4; int kw = r % 5; r /= 5; int kh = r % 5; int ci = r / 5;
    ws[P_WR2 + i] = w_c2[((co * 16 + ci) * 5 + kh) * 5 + kw];
  }
  for (int i = tid; i < 12544; i += 256) {
    int co = i & 15; int r = i >> 4; int kw = r % 7; r /= 7; int kh = r % 7; int ci = r / 7;
    ws[P_WR3 + i] = w_c3[((co * 16 + ci) * 7 + kh) * 7 + kw];
  }
  // wbr[((g*3+kw)*3+kh)*16+co] = w_base[co][g][kh][kw]
  for (int i = tid; i < 2304; i += 256) {
    int co = i & 15; int r = i >> 4; int kh = r % 3; r /= 3; int kw = r % 3; int g = r / 3;
    ws[P_WRB + i] = w_base[((co * 16 + g) * 3 + kh) * 3 + kw];
  }
  __syncthreads();
  // packed fp16 k3 weights: idx -> g (idx>>6), p ((idx>>3)&7), j (idx&7)
  // low half = e=2p, high half = e=2p+1  (RN via _Float16 casts)
  uint32_t* k3h  = (uint32_t*)(ws + P_K3H);
  uint32_t* k3sh = (uint32_t*)(ws + P_K3SH);
  for (int i = tid; i < 1024; i += 256) {
    int g = i >> 6, p = (i >> 3) & 7, j = i & 7;
    hv2 wv, wvs;
    wv.x  = (_Float16)ws[P_K3 + g * 128 + (2 * p) * 8 + j];
    wv.y  = (_Float16)ws[P_K3 + g * 128 + (2 * p + 1) * 8 + j];
    wvs.x = (_Float16)ws[P_K3S + g * 128 + (2 * p) * 8 + j];
    wvs.y = (_Float16)ws[P_K3S + g * 128 + (2 * p + 1) * 8 + j];
    k3h[i]  = __builtin_bit_cast(uint32_t, wv);
    k3sh[i] = __builtin_bit_cast(uint32_t, wvs);
  }
}

// ---------------- 1x1 conv 64->16, writes TRANSPOSED xT[b][ci][w][h] ----------------
__global__ __launch_bounds__(256) void k_in(const float* __restrict__ cen,
                                            const float* __restrict__ b_in,
                                            const float* __restrict__ ws,
                                            float* __restrict__ xT) {
  __shared__ float ldst[16 * 16 * 17];  // [co][tx(w)][ty(h)] padded to kill conflicts
  int tid = threadIdx.x;
  int b = blockIdx.z;
  int hbase = blockIdx.y * 16, wbase = blockIdx.x * 16;
  int ty = tid >> 4, tx = tid & 15;  // h, w within tile
  const float* wri = ws + P_WRI;
  float acc[16];
#pragma unroll
  for (int co = 0; co < 16; co++) acc[co] = b_in[co];
  const float* cp = cen + b * 64 * HW + (hbase + ty) * 256 + wbase + tx;
#pragma unroll 4
  for (int ci = 0; ci < 64; ci++) {
    float v = cp[ci * HW];
#pragma unroll
    for (int co = 0; co < 16; co++) acc[co] = fmaf(wri[ci * 16 + co], v, acc[co]);
  }
#pragma unroll
  for (int co = 0; co < 16; co++) ldst[(co * 16 + tx) * 17 + ty] = acc[co];
  __syncthreads();
  int wy = tid >> 4, hx = tid & 15;  // w, h for transposed write
#pragma unroll
  for (int ci = 0; ci < 16; ci++) {
    xT[((b * 16 + ci) << 16) + (wbase + wy) * 256 + hbase + hx] =
        ldst[(ci * 16 + wy) * 17 + hx];
  }
}

// ---------------- branch conv (k x k, 16->16), register-column, no LDS ----------------
// one wave per (b, w, 64h-segment); reads xT[b][ci][w][h], writes cT[b][co][w][h]
template <int KS>
__global__ __launch_bounds__(256) void k_conv(const float* __restrict__ xT,
                                              const float* __restrict__ bias,
                                              const float* __restrict__ wr,
                                              float* __restrict__ cT) {
  constexpr int P = KS / 2;
  const int tid = threadIdx.x;
  const int lane = tid & 63;
  const int wv = (blockIdx.x << 2) + (tid >> 6);  // 4096 waves: b(4) x w(256) x hseg(4)
  const int hseg = wv & 3;
  const int w = (wv >> 2) & 255;
  const int b = wv >> 10;
  const int hbase = hseg << 6;
  const float* xb = xT + ((b * 16) << 16);

  float acc[16];
#pragma unroll
  for (int co = 0; co < 16; co++) acc[co] = bias[co];

  for (int ci = 0; ci < 16; ci++) {
#pragma unroll
    for (int kw = 0; kw < KS; kw++) {
      const int wc = w + kw - P;
      if ((unsigned)wc >= 256u) continue;  // zero-pad: wave-uniform skip
      const float* col = xb + (ci << 16) + (wc << 8);
      // v0 holds col[hbase + lane - P], v1 holds col[hbase + 64 - P + lane] (lanes 0..2P-1)
      const int h0 = hbase + lane - P;
      float v0 = ((unsigned)h0 < 256u) ? col[h0] : 0.0f;
      float v1 = 0.0f;
      if (P > 0) {
        const int h1 = hbase + 64 - P + lane;
        v1 = (lane < 2 * P && (unsigned)h1 < 256u) ? col[h1] : 0.0f;
      }
#pragma unroll
      for (int kh = 0; kh < KS; kh++) {
        float tv;
        if (P == 0) {
          tv = v0;
        } else {
          const int s = lane + kh;  // tap source index in [0, 63+2P]
          float t0 = __shfl(v0, s & 63, 64);
          float t1 = __shfl(v1, (s - 64) & 63, 64);
          tv = (s < 64) ? t0 : t1;
        }
        const float* wp = wr + ((ci * KS + kh) * KS + kw) * 16;
#pragma unroll
        for (int co = 0; co < 16; co++) acc[co] = fmaf(wp[co], tv, acc[co]);
      }
    }
  }
  float* o = cT + ((b * 16) << 16) + (w << 8) + hbase + lane;
#pragma unroll
  for (int co = 0; co < 16; co++) o[co << 16] = acc[co];
}

// ---------------- packed-fp16 bitonic sort of 256 values: 64 lanes x 4 regs ----------------
// element i = 4*lane + r; each hv2 register sorts TWO independent channels in lockstep
__device__ __forceinline__ void ce_pair_h(hv2& a, hv2& b, bool up) {
  hv2 lo = __builtin_elementwise_min(a, b);
  hv2 hi = __builtin_elementwise_max(a, b);
  a = up ? lo : hi;
  b = up ? hi : lo;
}

template <int SIZE, int DIST>
__device__ __forceinline__ void stage_x_h(hv2 v[4], int i0) {
  const bool keepmin = (((i0 & DIST) == 0) == ((i0 & SIZE) == 0));
#pragma unroll
  for (int r = 0; r < 4; r++) {
    hv2 pv = i2h(__shfl_xor(h2i(v[r]), DIST >> 2, 64));
    hv2 lo = __builtin_elementwise_min(v[r], pv);
    hv2 hi = __builtin_elementwise_max(v[r], pv);
    v[r] = keepmin ? lo : hi;
  }
}

template <int SIZE>
__device__ __forceinline__ void stage_d21_h(hv2 v[4], int i0) {
  bool up = ((i0 & SIZE) == 0);
  ce_pair_h(v[0], v[2], up); ce_pair_h(v[1], v[3], up);
  ce_pair_h(v[0], v[1], up); ce_pair_h(v[2], v[3], up);
}

__device__ __forceinline__ void sort256h(hv2 v[4], int lane) {
  int i0 = lane << 2;
  ce_pair_h(v[0], v[1], true); ce_pair_h(v[2], v[3], false);   // size 2
  stage_d21_h<4>(v, i0);                                       // size 4
  stage_x_h<8, 4>(v, i0); stage_d21_h<8>(v, i0);
  stage_x_h<16, 8>(v, i0); stage_x_h<16, 4>(v, i0); stage_d21_h<16>(v, i0);
  stage_x_h<32, 16>(v, i0); stage_x_h<32, 8>(v, i0); stage_x_h<32, 4>(v, i0); stage_d21_h<32>(v, i0);
  stage_x_h<64, 32>(v, i0); stage_x_h<64, 16>(v, i0); stage_x_h<64, 8>(v, i0); stage_x_h<64, 4>(v, i0); stage_d21_h<64>(v, i0);
  stage_x_h<128, 64>(v, i0); stage_x_h<128, 32>(v, i0); stage_x_h<128, 16>(v, i0); stage_x_h<128, 8>(v, i0); stage_x_h<128, 4>(v, i0); stage_d21_h<128>(v, i0);
  stage_x_h<256, 128>(v, i0); stage_x_h<256, 64>(v, i0); stage_x_h<256, 32>(v, i0); stage_x_h<256, 16>(v, i0); stage_x_h<256, 8>(v, i0); stage_x_h<256, 4>(v, i0); stage_d21_h<256>(v, i0);
}

// ---------------- fused diff/k3/mul/sort/silu/k4 + branch max/sum accum ----------------
template <int DIL>
__global__ __launch_bounds__(256) void k_branch(const float* __restrict__ cT,
                                                const float* __restrict__ ws,
                                                float* __restrict__ maxb,
                                                float* __restrict__ sumb,
                                                int initFlag) {
  const int tid = threadIdx.x;
  const int lane = tid & 63;
  const int wv = (blockIdx.x << 2) + (tid >> 6);  // wave task id
  const int w = wv & 255;
  const int g = (wv >> 8) & 15;
  const int b = wv >> 12;
  const float* base = cT + ((b * 16 + g) << 16);

  float vals[3][3][4];
#pragma unroll
  for (int wi = 0; wi < 3; ++wi) {
    const int wc = w + (wi - 1) * DIL;
    const bool wok = ((unsigned)wc < 256u);
    const float* col = base + (wok ? wc : 0) * 256;
#pragma unroll
    for (int si = 0; si < 3; ++si) {
#pragma unroll
      for (int r = 0; r < 4; ++r) {
        const int h = lane + (r << 6) + (si - 1) * DIL;
        const bool ok = wok && ((unsigned)h < 256u);
        vals[wi][si][r] = ok ? col[h] : 0.0f;
      }
    }
  }
  // directional differences (fp32), then broadcast-pack to fp16x2 (one v_cvt_pkrtz each)
  hv2 ddh[8][4];
#pragma unroll
  for (int r = 0; r < 4; ++r) {
    const float c0 = vals[1][1][r];
    float d0 = c0 - vals[0][0][r];  // (h-d, w-d)
    float d1 = c0 - vals[1][0][r];  // (h-d, w)
    float d2 = c0 - vals[2][0][r];  // (h-d, w+d)
    float d3 = c0 - vals[0][1][r];  // (h,   w-d)
    float d4 = c0 - vals[2][2][r];  // (h+d, w+d)
    float d5 = c0 - vals[1][2][r];  // (h+d, w)
    float d6 = c0 - vals[0][2][r];  // (h+d, w-d)
    float d7 = c0 - vals[2][1][r];  // (h,   w+d)
    ddh[0][r] = pkrtz(d0, d0);
    ddh[1][r] = pkrtz(d1, d1);
    ddh[2][r] = pkrtz(d2, d2);
    ddh[3][r] = pkrtz(d3, d3);
    ddh[4][r] = pkrtz(d4, d4);
    ddh[5][r] = pkrtz(d5, d5);
    ddh[6][r] = pkrtz(d6, d6);
    ddh[7][r] = pkrtz(d7, d7);
  }
  float out[4] = {0.f, 0.f, 0.f, 0.f};
  const uint32_t* k3h  = (const uint32_t*)(ws + P_K3H)  + g * 64;
  const uint32_t* k3sh = (const uint32_t*)(ws + P_K3SH) + g * 64;
  const float* k4p = ws + P_K4 + g * 16;
#pragma unroll 1
  for (int p = 0; p < 8; ++p) {
    hv2 t[4];
#pragma unroll
    for (int r = 0; r < 4; ++r) {
      hv2 o1 = __builtin_bit_cast(hv2, k3h[p * 8]) * ddh[0][r];
      hv2 o2 = __builtin_bit_cast(hv2, k3sh[p * 8]) * ddh[0][r];
#pragma unroll
      for (int j = 1; j < 8; ++j) {
        o1 = pk_fma(__builtin_bit_cast(hv2, k3h[p * 8 + j]), ddh[j][r], o1);
        o2 = pk_fma(__builtin_bit_cast(hv2, k3sh[p * 8 + j]), ddh[j][r], o2);
      }
      t[r] = o1 * o2;
    }
    sort256h(t, lane);
    const float k4a = k4p[2 * p], k4b = k4p[2 * p + 1];
#pragma unroll
    for (int r = 0; r < 4; ++r) {
      const float va = (float)t[r].x;
      const float vb = (float)t[r].y;
      out[r] = fmaf(k4a, va * sigmoid_fast(va), out[r]);
      out[r] = fmaf(k4b, vb * sigmoid_fast(vb), out[r]);
    }
  }
  const int obase = (((b * 16 + g) << 8) + w) * 256 + (lane << 2);
  float4 o4 = make_float4(out[0], out[1], out[2], out[3]);
  float4* mp = (float4*)(maxb + obase);
  float4* sp = (float4*)(sumb + obase);
  if (initFlag) {
    *mp = o4;
    *sp = o4;
  } else {
    float4 m = *mp;
    m.x = fmaxf(m.x, o4.x); m.y = fmaxf(m.y, o4.y);
    m.z = fmaxf(m.z, o4.z); m.w = fmaxf(m.w, o4.w);
    *mp = m;
    float4 s = *sp;
    s.x += o4.x; s.y += o4.y; s.z += o4.z; s.w += o4.w;
    *sp = s;
  }
}

// ---------------- combine + 3x3 conv + BN + SiLU + 1x1 + sigmoid -> mask ----------------
__global__ __launch_bounds__(256) void k_tail(const float* __restrict__ maxb,
                                              const float* __restrict__ sumb,
                                              const float* __restrict__ ws,
                                              float* __restrict__ mask,
                                              const float* __restrict__ w_out,
                                              const float* __restrict__ b_out) {
  __shared__ float lds[16 * 18 * 18];
  __shared__ float ldsm[256];
  int tid = threadIdx.x;
  int b = blockIdx.z;
  int wbase = blockIdx.x * 16, hbase = blockIdx.y * 16;
  const float* mb = maxb + (b * 16) * HW;  // [g][w][h]
  const float* sb = sumb + (b * 16) * HW;
  for (int i = tid; i < 16 * 18 * 18; i += 256) {
    int g = i / 324; int r = i % 324; int xx = r / 18, yy = r % 18;
    int wq = wbase + xx - 1, hq = hbase + yy - 1;
    float v = 0.0f;
    if (wq >= 0 && wq < 256 && hq >= 0 && hq < 256) {
      int idx = g * HW + wq * 256 + hq;
      v = mb[idx] + 0.25f * sb[idx];
    }
    lds[i] = v;
  }
  __syncthreads();
  int xw = tid >> 4, yh = tid & 15;  // pixel (w = wbase+xw, h = hbase+yh)
  float acc[16] = {0.f, 0.f, 0.f, 0.f, 0.f, 0.f, 0.f, 0.f,
                   0.f, 0.f, 0.f, 0.f, 0.f, 0.f, 0.f, 0.f};
  for (int g = 0; g < 16; g++) {
#pragma unroll
    for (int kw = 0; kw < 3; kw++) {
#pragma unroll
      for (int kh = 0; kh < 3; kh++) {
        float v = lds[g * 324 + (xw + kw) * 18 + (yh + kh)];
        const float* wp = ws + P_WRB + ((g * 3 + kw) * 3 + kh) * 16;
#pragma unroll
        for (int co = 0; co < 16; co++) acc[co] = fmaf(wp[co], v, acc[co]);
      }
    }
  }
  float mo = b_out[0];
#pragma unroll
  for (int co = 0; co < 16; co++) {
    float z = acc[co] * ws[P_BNS + co] + ws[P_BNB + co];
    float sl = z * sigmoid_fast(z);
    mo = fmaf(w_out[co], sl, mo);
  }
  float mk = sigmoid_fast(mo);
  ldsm[yh * 16 + xw] = mk;
  __syncthreads();
  int yy = tid >> 4, xx = tid & 15;
  mask[b * HW + (hbase + yy) * 256 + wbase + xx] = ldsm[yy * 16 + xx];
}

// ---------------- final elementwise gate ----------------
__global__ __launch_bounds__(256) void k_final(const float* __restrict__ cen,
                                               const float* __restrict__ mas,
                                               const float* __restrict__ mask,
                                               const float* __restrict__ ws,
                                               float* __restrict__ out) {
  int q = blockIdx.x * 256 + threadIdx.x;  // pixel-quad id
  int b = q >> 14;
  int off = (q & 16383) << 2;
  int cbase = blockIdx.y * 16;
  float s0 = ws[P_S1], s1 = ws[P_S1 + 1], s2 = ws[P_S1 + 2], s3 = ws[P_S1 + 3];
  const float4 mk4 = *(const float4*)(mask + b * HW + off);
  const float4 ms4 = *(const float4*)(mas + b * HW + off);
  float f[4];
  {
    float mks[4] = {mk4.x, mk4.y, mk4.z, mk4.w};
    float mss[4] = {ms4.x, ms4.y, ms4.z, ms4.w};
#pragma unroll
    for (int k = 0; k < 4; k++) {
      float m = sigmoid_fast(mss[k]);
      f[k] = mks[k] * m * s0 + m * s1 + s2 * mks[k] + s3;
    }
  }
#pragma unroll 4
  for (int ci = cbase; ci < cbase + 16; ci++) {
    const float4 c4 = *(const float4*)(cen + (b * 64 + ci) * HW + off);
    float4 o4;
    o4.x = c4.x * f[0]; o4.y = c4.y * f[1]; o4.z = c4.z * f[2]; o4.w = c4.w * f[3];
    *(float4*)(out + (b * 64 + ci) * HW + off) = o4;
  }
}

extern "C" void kernel_launch(void* const* d_in, const int* in_sizes, int n_in,
                              void* d_out, int out_size, void* d_ws, size_t ws_size,
                              hipStream_t stream) {
  (void)in_sizes; (void)n_in; (void)out_size; (void)ws_size;
  const float* cen = (const float*)d_in[0];
  const float* mas = (const float*)d_in[1];
  const float* w_in = (const float*)d_in[2];
  const float* b_in = (const float*)d_in[3];
  const float* w_c0 = (const float*)d_in[4];
  const float* b_c0 = (const float*)d_in[5];
  const float* w_c1 = (const float*)d_in[6];
  const float* b_c1 = (const float*)d_in[7];
  const float* w_c2 = (const float*)d_in[8];
  const float* b_c2 = (const float*)d_in[9];
  const float* w_c3 = (const float*)d_in[10];
  const float* b_c3 = (const float*)d_in[11];
  const float* scales1 = (const float*)d_in[12];
  const float* scales2 = (const float*)d_in[13];
  const float* scales3 = (const float*)d_in[14];
  const float* w_base = (const float*)d_in[15];
  const float* bn_gamma = (const float*)d_in[16];
  const float* bn_beta = (const float*)d_in[17];
  const float* bn_mean = (const float*)d_in[18];
  const float* bn_var = (const float*)d_in[19];
  const float* w_out = (const float*)d_in[20];
  const float* b_out = (const float*)d_in[21];
  float* ws = (float*)d_ws;
  float* out = (float*)d_out;

  float* xT = ws + OFF_X;
  float* cT = ws + OFF_CT;
  float* maxb = ws + OFF_MAX;
  float* sumb = ws + OFF_SUM;
  float* mask = ws + OFF_MASK;

  k_prep<<<1, 256, 0, stream>>>(w_in, w_c0, w_c1, w_c2, w_c3, w_base, scales1, scales2,
                                scales3, bn_gamma, bn_beta, bn_mean, bn_var, ws);
  k_in<<<dim3(16, 16, 4), 256, 0, stream>>>(cen, b_in, ws, xT);

  k_conv<1><<<1024, 256, 0, stream>>>(xT, b_c0, ws + P_WR0, cT);
  k_branch<1><<<4096, 256, 0, stream>>>(cT, ws, maxb, sumb, 1);
  k_conv<3><<<1024, 256, 0, stream>>>(xT, b_c1, ws + P_WR1, cT);
  k_branch<3><<<4096, 256, 0, stream>>>(cT, ws, maxb, sumb, 0);
  k_conv<5><<<1024, 256, 0, stream>>>(xT, b_c2, ws + P_WR2, cT);
  k_branch<5><<<4096, 256, 0, stream>>>(cT, ws, maxb, sumb, 0);
  k_conv<7><<<1024, 256, 0, stream>>>(xT, b_c3, ws + P_WR3, cT);
  k_branch<7><<<4096, 256, 0, stream>>>(cT, ws, maxb, sumb, 0);

  k_tail<<<dim3(16, 16, 4), 256, 0, stream>>>(maxb, sumb, ws, mask, w_out, b_out);
  k_final<<<dim3(256, 4), 256, 0, stream>>>(cen, mas, mask, ws, out);
}

// Round 7
// 915.046 us; speedup vs baseline: 1.5688x; 1.0655x over previous
//
#include <hip/hip_runtime.h>

#define HW 65536

// ---- ws layout (float offsets) ----
constexpr int OFF_X    = 0;          // xT: 4b*16ci*256w*256h (transposed)
constexpr int OFF_CT   = 4194304;    // c transposed [b][g][w][h]
constexpr int OFF_MAX  = 8388608;
constexpr int OFF_SUM  = 12582912;
constexpr int OFF_MASK = 16777216;   // 262144
constexpr int P_K3  = 17039360;          // 256*8 softmax(scales2)
constexpr int P_K3S = P_K3  + 2048;      // shifted (j+4)%8
constexpr int P_K4  = P_K3S + 2048;      // 16*16 softmax(scales3)
constexpr int P_S1  = P_K4  + 256;       // softmax(scales1), 4
constexpr int P_BNS = P_S1  + 4;         // 16
constexpr int P_BNB = P_BNS + 16;        // 16
constexpr int P_WRI = P_BNB + 16;        // w_in  re-laid [ci][co] 1024
constexpr int P_WR0 = P_WRI + 1024;      // 256
constexpr int P_WR1 = P_WR0 + 256;       // 2304
constexpr int P_WR2 = P_WR1 + 2304;      // 6400
constexpr int P_WR3 = P_WR2 + 6400;      // 12544
constexpr int P_WRB = P_WR3 + 12544;     // 2304
constexpr int P_K3H  = P_WRB + 2304;     // packed fp16 pairs: 16g*8p*8j = 1024 (uint32)
constexpr int P_K3SH = P_K3H + 1024;     // 1024

// clang-native packed fp16
typedef _Float16 hv2 __attribute__((ext_vector_type(2)));

__device__ __forceinline__ int h2i(hv2 v) { return __builtin_bit_cast(int, v); }
__device__ __forceinline__ hv2 i2h(int v) { return __builtin_bit_cast(hv2, v); }

// __builtin_amdgcn_cvt_pkrtz returns __fp16 ext_vector(2); bit-cast to hv2
__device__ __forceinline__ hv2 pkrtz(float a, float b) {
  return __builtin_bit_cast(hv2, __builtin_amdgcn_cvt_pkrtz(a, b));
}

// guaranteed-packed fp16 ops (one VOP3P inst each)
__device__ __forceinline__ hv2 pkmin(hv2 a, hv2 b) {
  hv2 d; asm("v_pk_min_f16 %0, %1, %2" : "=v"(d) : "v"(a), "v"(b)); return d;
}
__device__ __forceinline__ hv2 pkmax(hv2 a, hv2 b) {
  hv2 d; asm("v_pk_max_f16 %0, %1, %2" : "=v"(d) : "v"(a), "v"(b)); return d;
}
__device__ __forceinline__ hv2 pkmul(hv2 a, hv2 b) {
  hv2 d; asm("v_pk_mul_f16 %0, %1, %2" : "=v"(d) : "v"(a), "v"(b)); return d;
}
__device__ __forceinline__ hv2 pkfma(hv2 a, hv2 b, hv2 c) {
  hv2 d; asm("v_pk_fma_f16 %0, %1, %2, %3" : "=v"(d) : "v"(a), "v"(b), "v"(c)); return d;
}

// 32-bit select -> single v_cndmask_b32
__device__ __forceinline__ hv2 sel32(bool c, hv2 a, hv2 b) {
  return i2h(c ? h2i(a) : h2i(b));
}

// cross-lane xor: ds_swizzle (0 VALU) for mask<32, shfl for 32
template <int LMASK>
__device__ __forceinline__ int lane_xor_i(int x) {
  if constexpr (LMASK < 32) {
    return __builtin_amdgcn_ds_swizzle(x, (LMASK << 10) | 0x1F);
  } else {
    return __shfl_xor(x, LMASK, 64);
  }
}

__device__ __forceinline__ float sigmoid_fast(float x) {
  return __fdividef(1.0f, 1.0f + __expf(-x));
}

// ---------------- prep ----------------
__global__ void k_prep(const float* __restrict__ w_in, const float* __restrict__ w_c0,
                       const float* __restrict__ w_c1, const float* __restrict__ w_c2,
                       const float* __restrict__ w_c3, const float* __restrict__ w_base,
                       const float* __restrict__ scales1, const float* __restrict__ scales2,
                       const float* __restrict__ scales3, const float* __restrict__ bn_gamma,
                       const float* __restrict__ bn_beta, const float* __restrict__ bn_mean,
                       const float* __restrict__ bn_var, float* __restrict__ ws) {
  int tid = threadIdx.x;  // 256
  {
    const float* srow = scales2 + tid * 8;
    float v[8]; float mx = -1e30f;
    for (int j = 0; j < 8; j++) { v[j] = srow[j]; mx = fmaxf(mx, v[j]); }
    float s = 0.f;
    for (int j = 0; j < 8; j++) { v[j] = __expf(v[j] - mx); s += v[j]; }
    float inv = 1.0f / s;
    for (int j = 0; j < 8; j++) ws[P_K3 + tid * 8 + j] = v[j] * inv;
    for (int j = 0; j < 8; j++) ws[P_K3S + tid * 8 + j] = v[(j + 4) & 7] * inv;
  }
  if (tid < 16) {
    const float* srow = scales3 + tid * 16;
    float v[16]; float mx = -1e30f;
    for (int e = 0; e < 16; e++) { v[e] = srow[e]; mx = fmaxf(mx, v[e]); }
    float s = 0.f;
    for (int e = 0; e < 16; e++) { v[e] = __expf(v[e] - mx); s += v[e]; }
    float inv = 1.0f / s;
    for (int e = 0; e < 16; e++) ws[P_K4 + tid * 16 + e] = v[e] * inv;
  }
  if (tid == 0) {
    float v[4]; float mx = -1e30f;
    for (int i = 0; i < 4; i++) { v[i] = scales1[i]; mx = fmaxf(mx, v[i]); }
    float s = 0.f;
    for (int i = 0; i < 4; i++) { v[i] = __expf(v[i] - mx); s += v[i]; }
    for (int i = 0; i < 4; i++) ws[P_S1 + i] = v[i] / s;
  }
  if (tid < 16) {
    float rs = rsqrtf(bn_var[tid] + 1e-5f);
    float sc = bn_gamma[tid] * rs;
    ws[P_BNS + tid] = sc;
    ws[P_BNB + tid] = bn_beta[tid] - bn_mean[tid] * sc;
  }
  for (int i = tid; i < 1024; i += 256) { int ci = i >> 4, co = i & 15; ws[P_WRI + i] = w_in[co * 64 + ci]; }
  for (int i = tid; i < 256; i += 256)  { int ci = i >> 4, co = i & 15; ws[P_WR0 + i] = w_c0[co * 16 + ci]; }
  for (int i = tid; i < 2304; i += 256) {
    int co = i & 15; int r = i >> 4; int kw = r % 3; r /= 3; int kh = r % 3; int ci = r / 3;
    ws[P_WR1 + i] = w_c1[((co * 16 + ci) * 3 + kh) * 3 + kw];
  }
  for (int i = tid; i < 6400; i += 256) {
    int co = i & 15; int r = i >> 4; int kw = r % 5; r /= 5; int kh = r % 5; int ci = r / 5;
    ws[P_WR2 + i] = w_c2[((co * 16 + ci) * 5 + kh) * 5 + kw];
  }
  for (int i = tid; i < 12544; i += 256) {
    int co = i & 15; int r = i >> 4; int kw = r % 7; r /= 7; int kh = r % 7; int ci = r / 7;
    ws[P_WR3 + i] = w_c3[((co * 16 + ci) * 7 + kh) * 7 + kw];
  }
  // wbr[((g*3+kw)*3+kh)*16+co] = w_base[co][g][kh][kw]
  for (int i = tid; i < 2304; i += 256) {
    int co = i & 15; int r = i >> 4; int kh = r % 3; r /= 3; int kw = r % 3; int g = r / 3;
    ws[P_WRB + i] = w_base[((co * 16 + g) * 3 + kh) * 3 + kw];
  }
  __syncthreads();
  // packed fp16 k3 weights: idx -> g (idx>>6), p ((idx>>3)&7), j (idx&7)
  // low half = e=2p, high half = e=2p+1  (RN via _Float16 casts)
  uint32_t* k3h  = (uint32_t*)(ws + P_K3H);
  uint32_t* k3sh = (uint32_t*)(ws + P_K3SH);
  for (int i = tid; i < 1024; i += 256) {
    int g = i >> 6, p = (i >> 3) & 7, j = i & 7;
    hv2 wv, wvs;
    wv.x  = (_Float16)ws[P_K3 + g * 128 + (2 * p) * 8 + j];
    wv.y  = (_Float16)ws[P_K3 + g * 128 + (2 * p + 1) * 8 + j];
    wvs.x = (_Float16)ws[P_K3S + g * 128 + (2 * p) * 8 + j];
    wvs.y = (_Float16)ws[P_K3S + g * 128 + (2 * p + 1) * 8 + j];
    k3h[i]  = __builtin_bit_cast(uint32_t, wv);
    k3sh[i] = __builtin_bit_cast(uint32_t, wvs);
  }
}

// ---------------- 1x1 conv 64->16, writes TRANSPOSED xT[b][ci][w][h] ----------------
__global__ __launch_bounds__(256) void k_in(const float* __restrict__ cen,
                                            const float* __restrict__ b_in,
                                            const float* __restrict__ ws,
                                            float* __restrict__ xT) {
  __shared__ float ldst[16 * 16 * 17];  // [co][tx(w)][ty(h)] padded
  int tid = threadIdx.x;
  int b = blockIdx.z;
  int hbase = blockIdx.y * 16, wbase = blockIdx.x * 16;
  int ty = tid >> 4, tx = tid & 15;  // h, w within tile
  const float* wri = ws + P_WRI;
  float acc[16];
#pragma unroll
  for (int co = 0; co < 16; co++) acc[co] = b_in[co];
  const float* cp = cen + b * 64 * HW + (hbase + ty) * 256 + wbase + tx;
#pragma unroll 4
  for (int ci = 0; ci < 64; ci++) {
    float v = cp[ci * HW];
#pragma unroll
    for (int co = 0; co < 16; co++) acc[co] = fmaf(wri[ci * 16 + co], v, acc[co]);
  }
#pragma unroll
  for (int co = 0; co < 16; co++) ldst[(co * 16 + tx) * 17 + ty] = acc[co];
  __syncthreads();
  int wy = tid >> 4, hx = tid & 15;  // w, h for transposed write
#pragma unroll
  for (int ci = 0; ci < 16; ci++) {
    xT[((b * 16 + ci) << 16) + (wbase + wy) * 256 + hbase + hx] =
        ldst[(ci * 16 + wy) * 17 + hx];
  }
}

// ---------------- branch conv (k x k, 16->16), register-column, no LDS ----------------
template <int KS>
__global__ __launch_bounds__(256) void k_conv(const float* __restrict__ xT,
                                              const float* __restrict__ bias,
                                              const float* __restrict__ wr,
                                              float* __restrict__ cT) {
  constexpr int P = KS / 2;
  const int tid = threadIdx.x;
  const int lane = tid & 63;
  const int wv = (blockIdx.x << 2) + (tid >> 6);  // 4096 waves: b(4) x w(256) x hseg(4)
  const int hseg = wv & 3;
  const int w = (wv >> 2) & 255;
  const int b = wv >> 10;
  const int hbase = hseg << 6;
  const float* xb = xT + ((b * 16) << 16);

  float acc[16];
#pragma unroll
  for (int co = 0; co < 16; co++) acc[co] = bias[co];

  for (int ci = 0; ci < 16; ci++) {
#pragma unroll
    for (int kw = 0; kw < KS; kw++) {
      const int wc = w + kw - P;
      if ((unsigned)wc >= 256u) continue;  // zero-pad: wave-uniform skip
      const float* col = xb + (ci << 16) + (wc << 8);
      const int h0 = hbase + lane - P;
      float v0 = ((unsigned)h0 < 256u) ? col[h0] : 0.0f;
      float v1 = 0.0f;
      if (P > 0) {
        const int h1 = hbase + 64 - P + lane;
        v1 = (lane < 2 * P && (unsigned)h1 < 256u) ? col[h1] : 0.0f;
      }
#pragma unroll
      for (int kh = 0; kh < KS; kh++) {
        float tv;
        if (P == 0) {
          tv = v0;
        } else {
          const int s = lane + kh;  // tap source index in [0, 63+2P]
          float t0 = __shfl(v0, s & 63, 64);
          float t1 = __shfl(v1, (s - 64) & 63, 64);
          tv = (s < 64) ? t0 : t1;
        }
        const float* wp = wr + ((ci * KS + kh) * KS + kw) * 16;
#pragma unroll
        for (int co = 0; co < 16; co++) acc[co] = fmaf(wp[co], tv, acc[co]);
      }
    }
  }
  float* o = cT + ((b * 16) << 16) + (w << 8) + hbase + lane;
#pragma unroll
  for (int co = 0; co < 16; co++) o[co << 16] = acc[co];
}

// ---------------- packed-fp16 bitonic sort of 256 values: 64 lanes x 4 regs ----------------
// element i = 4*lane + r; each hv2 register sorts TWO independent channels in lockstep
__device__ __forceinline__ void ce_pair_h(hv2& a, hv2& b, bool up) {
  hv2 lo = pkmin(a, b);
  hv2 hi = pkmax(a, b);
  a = sel32(up, lo, hi);
  b = sel32(up, hi, lo);
}

template <int SIZE, int DIST>
__device__ __forceinline__ void stage_x_h(hv2 v[4], int i0) {
  const bool keepmin = (((i0 & DIST) == 0) == ((i0 & SIZE) == 0));
#pragma unroll
  for (int r = 0; r < 4; r++) {
    hv2 pv = i2h(lane_xor_i<(DIST >> 2)>(h2i(v[r])));
    v[r] = sel32(keepmin, pkmin(v[r], pv), pkmax(v[r], pv));
  }
}

template <int SIZE>
__device__ __forceinline__ void stage_d21_h(hv2 v[4], int i0) {
  bool up = ((i0 & SIZE) == 0);
  ce_pair_h(v[0], v[2], up); ce_pair_h(v[1], v[3], up);
  ce_pair_h(v[0], v[1], up); ce_pair_h(v[2], v[3], up);
}

__device__ __forceinline__ void sort256h(hv2 v[4], int lane) {
  int i0 = lane << 2;
  ce_pair_h(v[0], v[1], true); ce_pair_h(v[2], v[3], false);   // size 2
  stage_d21_h<4>(v, i0);                                       // size 4
  stage_x_h<8, 4>(v, i0); stage_d21_h<8>(v, i0);
  stage_x_h<16, 8>(v, i0); stage_x_h<16, 4>(v, i0); stage_d21_h<16>(v, i0);
  stage_x_h<32, 16>(v, i0); stage_x_h<32, 8>(v, i0); stage_x_h<32, 4>(v, i0); stage_d21_h<32>(v, i0);
  stage_x_h<64, 32>(v, i0); stage_x_h<64, 16>(v, i0); stage_x_h<64, 8>(v, i0); stage_x_h<64, 4>(v, i0); stage_d21_h<64>(v, i0);
  stage_x_h<128, 64>(v, i0); stage_x_h<128, 32>(v, i0); stage_x_h<128, 16>(v, i0); stage_x_h<128, 8>(v, i0); stage_x_h<128, 4>(v, i0); stage_d21_h<128>(v, i0);
  stage_x_h<256, 128>(v, i0); stage_x_h<256, 64>(v, i0); stage_x_h<256, 32>(v, i0); stage_x_h<256, 16>(v, i0); stage_x_h<256, 8>(v, i0); stage_x_h<256, 4>(v, i0); stage_d21_h<256>(v, i0);
}

// ---------------- fused diff/k3/mul/sort/silu/k4 + branch max/sum accum ----------------
template <int DIL>
__global__ __launch_bounds__(256) void k_branch(const float* __restrict__ cT,
                                                const float* __restrict__ ws,
                                                float* __restrict__ maxb,
                                                float* __restrict__ sumb,
                                                int initFlag) {
  const int tid = threadIdx.x;
  const int lane = tid & 63;
  // wave-uniform task id via readfirstlane -> scalar addressing + s_load weights
  const int wid = __builtin_amdgcn_readfirstlane(tid >> 6);
  const int wv = (blockIdx.x << 2) + wid;
  const int w = wv & 255;
  const int g = (wv >> 8) & 15;
  const int b = wv >> 12;
  const float* base = cT + ((b * 16 + g) << 16);

  float vals[3][3][4];
#pragma unroll
  for (int wi = 0; wi < 3; ++wi) {
    const int wc = w + (wi - 1) * DIL;
    const bool wok = ((unsigned)wc < 256u);
    const float* col = base + (wok ? wc : 0) * 256;
#pragma unroll
    for (int si = 0; si < 3; ++si) {
#pragma unroll
      for (int r = 0; r < 4; ++r) {
        const int h = lane + (r << 6) + (si - 1) * DIL;
        const bool ok = wok && ((unsigned)h < 256u);
        vals[wi][si][r] = ok ? col[h] : 0.0f;
      }
    }
  }
  // directional differences (fp32), then broadcast-pack to fp16x2
  hv2 ddh[8][4];
#pragma unroll
  for (int r = 0; r < 4; ++r) {
    const float c0 = vals[1][1][r];
    float d0 = c0 - vals[0][0][r];  // (h-d, w-d)
    float d1 = c0 - vals[1][0][r];  // (h-d, w)
    float d2 = c0 - vals[2][0][r];  // (h-d, w+d)
    float d3 = c0 - vals[0][1][r];  // (h,   w-d)
    float d4 = c0 - vals[2][2][r];  // (h+d, w+d)
    float d5 = c0 - vals[1][2][r];  // (h+d, w)
    float d6 = c0 - vals[0][2][r];  // (h+d, w-d)
    float d7 = c0 - vals[2][1][r];  // (h,   w+d)
    ddh[0][r] = pkrtz(d0, d0);
    ddh[1][r] = pkrtz(d1, d1);
    ddh[2][r] = pkrtz(d2, d2);
    ddh[3][r] = pkrtz(d3, d3);
    ddh[4][r] = pkrtz(d4, d4);
    ddh[5][r] = pkrtz(d5, d5);
    ddh[6][r] = pkrtz(d6, d6);
    ddh[7][r] = pkrtz(d7, d7);
  }
  float out[4] = {0.f, 0.f, 0.f, 0.f};
  const uint32_t* k3h  = (const uint32_t*)(ws + P_K3H)  + g * 64;
  const uint32_t* k3sh = (const uint32_t*)(ws + P_K3SH) + g * 64;
  const float* k4p = ws + P_K4 + g * 16;
#pragma unroll 1
  for (int p = 0; p < 8; ++p) {
    hv2 t[4];
    hv2 wk3[8], wk3s[8];
#pragma unroll
    for (int j = 0; j < 8; ++j) {
      wk3[j]  = i2h((int)k3h[p * 8 + j]);
      wk3s[j] = i2h((int)k3sh[p * 8 + j]);
    }
#pragma unroll
    for (int r = 0; r < 4; ++r) {
      hv2 o1 = pkmul(wk3[0], ddh[0][r]);
      hv2 o2 = pkmul(wk3s[0], ddh[0][r]);
#pragma unroll
      for (int j = 1; j < 8; ++j) {
        o1 = pkfma(wk3[j], ddh[j][r], o1);
        o2 = pkfma(wk3s[j], ddh[j][r], o2);
      }
      t[r] = pkmul(o1, o2);
    }
    sort256h(t, lane);
    const float k4a = k4p[2 * p], k4b = k4p[2 * p + 1];
#pragma unroll
    for (int r = 0; r < 4; ++r) {
      const float va = (float)t[r].x;
      const float vb = (float)t[r].y;
      out[r] = fmaf(k4a, va * sigmoid_fast(va), out[r]);
      out[r] = fmaf(k4b, vb * sigmoid_fast(vb), out[r]);
    }
  }
  const int obase = (((b * 16 + g) << 8) + w) * 256 + (lane << 2);
  float4 o4 = make_float4(out[0], out[1], out[2], out[3]);
  float4* mp = (float4*)(maxb + obase);
  float4* sp = (float4*)(sumb + obase);
  if (initFlag) {
    *mp = o4;
    *sp = o4;
  } else {
    float4 m = *mp;
    m.x = fmaxf(m.x, o4.x); m.y = fmaxf(m.y, o4.y);
    m.z = fmaxf(m.z, o4.z); m.w = fmaxf(m.w, o4.w);
    *mp = m;
    float4 s = *sp;
    s.x += o4.x; s.y += o4.y; s.z += o4.z; s.w += o4.w;
    *sp = s;
  }
}

// ---------------- combine + 3x3 conv + BN + SiLU + 1x1 + sigmoid -> mask ----------------
__global__ __launch_bounds__(256) void k_tail(const float* __restrict__ maxb,
                                              const float* __restrict__ sumb,
                                              const float* __restrict__ ws,
                                              float* __restrict__ mask,
                                              const float* __restrict__ w_out,
                                              const float* __restrict__ b_out) {
  __shared__ float lds[16 * 18 * 18];
  __shared__ float ldsm[256];
  int tid = threadIdx.x;
  int b = blockIdx.z;
  int wbase = blockIdx.x * 16, hbase = blockIdx.y * 16;
  const float* mb = maxb + (b * 16) * HW;  // [g][w][h]
  const float* sb = sumb + (b * 16) * HW;
  for (int i = tid; i < 16 * 18 * 18; i += 256) {
    int g = i / 324; int r = i % 324; int xx = r / 18, yy = r % 18;
    int wq = wbase + xx - 1, hq = hbase + yy - 1;
    float v = 0.0f;
    if (wq >= 0 && wq < 256 && hq >= 0 && hq < 256) {
      int idx = g * HW + wq * 256 + hq;
      v = mb[idx] + 0.25f * sb[idx];
    }
    lds[i] = v;
  }
  __syncthreads();
  int xw = tid >> 4, yh = tid & 15;  // pixel (w = wbase+xw, h = hbase+yh)
  float acc[16] = {0.f, 0.f, 0.f, 0.f, 0.f, 0.f, 0.f, 0.f,
                   0.f, 0.f, 0.f, 0.f, 0.f, 0.f, 0.f, 0.f};
  for (int g = 0; g < 16; g++) {
#pragma unroll
    for (int kw = 0; kw < 3; kw++) {
#pragma unroll
      for (int kh = 0; kh < 3; kh++) {
        float v = lds[g * 324 + (xw + kw) * 18 + (yh + kh)];
        const float* wp = ws + P_WRB + ((g * 3 + kw) * 3 + kh) * 16;
#pragma unroll
        for (int co = 0; co < 16; co++) acc[co] = fmaf(wp[co], v, acc[co]);
      }
    }
  }
  float mo = b_out[0];
#pragma unroll
  for (int co = 0; co < 16; co++) {
    float z = acc[co] * ws[P_BNS + co] + ws[P_BNB + co];
    float sl = z * sigmoid_fast(z);
    mo = fmaf(w_out[co], sl, mo);
  }
  float mk = sigmoid_fast(mo);
  ldsm[yh * 16 + xw] = mk;
  __syncthreads();
  int yy = tid >> 4, xx = tid & 15;
  mask[b * HW + (hbase + yy) * 256 + wbase + xx] = ldsm[yy * 16 + xx];
}

// ---------------- final elementwise gate ----------------
__global__ __launch_bounds__(256) void k_final(const float* __restrict__ cen,
                                               const float* __restrict__ mas,
                                               const float* __restrict__ mask,
                                               const float* __restrict__ ws,
                                               float* __restrict__ out) {
  int q = blockIdx.x * 256 + threadIdx.x;  // pixel-quad id
  int b = q >> 14;
  int off = (q & 16383) << 2;
  int cbase = blockIdx.y * 16;
  float s0 = ws[P_S1], s1 = ws[P_S1 + 1], s2 = ws[P_S1 + 2], s3 = ws[P_S1 + 3];
  const float4 mk4 = *(const float4*)(mask + b * HW + off);
  const float4 ms4 = *(const float4*)(mas + b * HW + off);
  float f[4];
  {
    float mks[4] = {mk4.x, mk4.y, mk4.z, mk4.w};
    float mss[4] = {ms4.x, ms4.y, ms4.z, ms4.w};
#pragma unroll
    for (int k = 0; k < 4; k++) {
      float m = sigmoid_fast(mss[k]);
      f[k] = mks[k] * m * s0 + m * s1 + s2 * mks[k] + s3;
    }
  }
#pragma unroll 4
  for (int ci = cbase; ci < cbase + 16; ci++) {
    const float4 c4 = *(const float4*)(cen + (b * 64 + ci) * HW + off);
    float4 o4;
    o4.x = c4.x * f[0]; o4.y = c4.y * f[1]; o4.z = c4.z * f[2]; o4.w = c4.w * f[3];
    *(float4*)(out + (b * 64 + ci) * HW + off) = o4;
  }
}

extern "C" void kernel_launch(void* const* d_in, const int* in_sizes, int n_in,
                              void* d_out, int out_size, void* d_ws, size_t ws_size,
                              hipStream_t stream) {
  (void)in_sizes; (void)n_in; (void)out_size; (void)ws_size;
  const float* cen = (const float*)d_in[0];
  const float* mas = (const float*)d_in[1];
  const float* w_in = (const float*)d_in[2];
  const float* b_in = (const float*)d_in[3];
  const float* w_c0 = (const float*)d_in[4];
  const float* b_c0 = (const float*)d_in[5];
  const float* w_c1 = (const float*)d_in[6];
  const float* b_c1 = (const float*)d_in[7];
  const float* w_c2 = (const float*)d_in[8];
  const float* b_c2 = (const float*)d_in[9];
  const float* w_c3 = (const float*)d_in[10];
  const float* b_c3 = (const float*)d_in[11];
  const float* scales1 = (const float*)d_in[12];
  const float* scales2 = (const float*)d_in[13];
  const float* scales3 = (const float*)d_in[14];
  const float* w_base = (const float*)d_in[15];
  const float* bn_gamma = (const float*)d_in[16];
  const float* bn_beta = (const float*)d_in[17];
  const float* bn_mean = (const float*)d_in[18];
  const float* bn_var = (const float*)d_in[19];
  const float* w_out = (const float*)d_in[20];
  const float* b_out = (const float*)d_in[21];
  float* ws = (float*)d_ws;
  float* out = (float*)d_out;

  float* xT = ws + OFF_X;
  float* cT = ws + OFF_CT;
  float* maxb = ws + OFF_MAX;
  float* sumb = ws + OFF_SUM;
  float* mask = ws + OFF_MASK;

  k_prep<<<1, 256, 0, stream>>>(w_in, w_c0, w_c1, w_c2, w_c3, w_base, scales1, scales2,
                                scales3, bn_gamma, bn_beta, bn_mean, bn_var, ws);
  k_in<<<dim3(16, 16, 4), 256, 0, stream>>>(cen, b_in, ws, xT);

  k_conv<1><<<1024, 256, 0, stream>>>(xT, b_c0, ws + P_WR0, cT);
  k_branch<1><<<4096, 256, 0, stream>>>(cT, ws, maxb, sumb, 1);
  k_conv<3><<<1024, 256, 0, stream>>>(xT, b_c1, ws + P_WR1, cT);
  k_branch<3><<<4096, 256, 0, stream>>>(cT, ws, maxb, sumb, 0);
  k_conv<5><<<1024, 256, 0, stream>>>(xT, b_c2, ws + P_WR2, cT);
  k_branch<5><<<4096, 256, 0, stream>>>(cT, ws, maxb, sumb, 0);
  k_conv<7><<<1024, 256, 0, stream>>>(xT, b_c3, ws + P_WR3, cT);
  k_branch<7><<<4096, 256, 0, stream>>>(cT, ws, maxb, sumb, 0);

  k_tail<<<dim3(16, 16, 4), 256, 0, stream>>>(maxb, sumb, ws, mask, w_out, b_out);
  k_final<<<dim3(256, 4), 256, 0, stream>>>(cen, mas, mask, ws, out);
}